// Round 4
// baseline (1367.619 us; speedup 1.0000x reference)
//
#include <hip/hip_runtime.h>
#include <stdint.h>

typedef unsigned short u16;
typedef unsigned int u32;

#define T_TOK 8192      // B*S tokens
#define DIMSZ 1024
#define HIDSZ 1024
#define NE 8
#define NSLOT (T_TOK * 2)
#define NPAD (NSLOT + 1024)   // segment-aligned slot capacity
// NOTE: 256-row GEMM tiles may over-READ up to 255 rows past a segment's
// padded end; those reads land in the adjacent workspace buffer (benign,
// results masked on write). Keep workspace buffer order: routed->Hbuf->Orb.

typedef __attribute__((ext_vector_type(8))) __bf16 bf16x8;
typedef __attribute__((ext_vector_type(16))) float f32x16;

#define MFMA32(a, b, c) __builtin_amdgcn_mfma_f32_32x32x16_bf16(a, b, c, 0, 0, 0)

// ---- blocked tile layouts (all GEMM operands, K = 1024, KT = 32) ----------
// A (activations, 128-row tiles):  [mt][kt][kc][row(128)][8]  (8 KB / tile)
// W (weights, 64-row tiles):       [nt][kt][kc][col(64)][8]   (4 KB / tile)
__device__ __forceinline__ size_t ablk(int pos, int c) {
  return ((((size_t)(pos >> 7) * 32 + (c >> 5)) * 4 + ((c >> 3) & 3)) * 128 +
          (pos & 127)) * 8 + (c & 7);
}

__device__ __forceinline__ u16 f2bf(float f) {
  u32 u = __builtin_bit_cast(u32, f);
  u += 0x7FFFu + ((u >> 16) & 1u);   // RNE
  return (u16)(u >> 16);
}
__device__ __forceinline__ float bflo(u32 v) { return __builtin_bit_cast(float, v << 16); }
__device__ __forceinline__ float bfhi(u32 v) { return __builtin_bit_cast(float, v & 0xffff0000u); }
__device__ __forceinline__ u32 pack2(float a, float b) {
  return (u32)f2bf(a) | ((u32)f2bf(b) << 16);
}
__device__ __forceinline__ float silu_f(float v) { return v / (1.f + expf(-v)); }

// ---- async global->LDS, 16 B per lane (global_load_lds_dwordx4) -----------
__device__ __forceinline__ void gload16(const void* g, void* l) {
  __builtin_amdgcn_global_load_lds(
      (const __attribute__((address_space(1))) unsigned int*)g,
      (__attribute__((address_space(3))) unsigned int*)l, 16, 0, 0);
}

// counted-vmcnt barrier: wait until <=N of this wave's global_load_lds remain
// outstanding, then s_barrier (single asm so nothing schedules between).
#define PIPE_SYNC(N) asm volatile("s_waitcnt vmcnt(" #N ")\n\ts_barrier" ::: "memory")

// ---------------- weight convert: fp32 row-major -> bf16 blocked (1 launch) --
__global__ __launch_bounds__(256) void convert_blocked(
    const float* __restrict__ s0, const float* __restrict__ s1,
    const float* __restrict__ s2, const float* __restrict__ ss0,
    const float* __restrict__ ss1, const float* __restrict__ ss2,
    u16* __restrict__ d0, u16* __restrict__ d1, u16* __restrict__ d2,
    u16* __restrict__ ds0, u16* __restrict__ ds1, u16* __restrict__ ds2) {
  __shared__ u16 lt[2048];
  int t = blockIdx.x;
  const float* s;
  u16* d;
  if (t < NE * 16 * 32) {
    s = (blockIdx.y == 0) ? s0 : (blockIdx.y == 1) ? s1 : s2;
    d = (blockIdx.y == 0) ? d0 : (blockIdx.y == 1) ? d1 : d2;
  } else {
    t -= NE * 16 * 32;
    s = (blockIdx.y == 0) ? ss0 : (blockIdx.y == 1) ? ss1 : ss2;
    d = (blockIdx.y == 0) ? ds0 : (blockIdx.y == 1) ? ds1 : ds2;
  }
  int rt = t >> 5, kt = t & 31;           // 64-row group, k-tile
  const float* sp = s + (size_t)rt * 64 * 1024 + kt * 32;
  int nl = threadIdx.x >> 2, k0 = (threadIdx.x & 3) * 8;
  float4 a = *(const float4*)(sp + (size_t)nl * 1024 + k0);
  float4 b = *(const float4*)(sp + (size_t)nl * 1024 + k0 + 4);
  uint4 p;
  p.x = pack2(a.x, a.y); p.y = pack2(a.z, a.w);
  p.z = pack2(b.x, b.y); p.w = pack2(b.z, b.w);
  *(uint4*)&lt[(threadIdx.x & 3) * 512 + nl * 8] = p;   // [kc][col][8]
  __syncthreads();
  *(uint4*)(d + (size_t)t * 2048 + threadIdx.x * 8) = *(const uint4*)&lt[threadIdx.x * 8];
}

// ---------------- router: fp32 scores, top-2; emits blocked bf16(x) ----------
__global__ __launch_bounds__(256) void router_kernel(
    const float* __restrict__ x, const float* __restrict__ gw,
    const float* __restrict__ bias, int* __restrict__ sel,
    float* __restrict__ selscore, u16* __restrict__ xb) {
  int t = blockIdx.x * 4 + (threadIdx.x >> 6);
  int lane = threadIdx.x & 63;
  float a[NE];
#pragma unroll
  for (int e = 0; e < NE; e++) a[e] = 0.f;
#pragma unroll
  for (int j = 0; j < 4; j++) {
    int c = j * 256 + lane * 4;
    float4 xv = *(const float4*)&x[(size_t)t * DIMSZ + c];
    uint2 p;
    p.x = pack2(xv.x, xv.y);
    p.y = pack2(xv.z, xv.w);
    *(uint2*)&xb[ablk(t, c)] = p;
#pragma unroll
    for (int e = 0; e < NE; e++) {
      float4 gv = *(const float4*)&gw[e * DIMSZ + c];
      a[e] = fmaf(xv.x, gv.x, fmaf(xv.y, gv.y, fmaf(xv.z, gv.z, fmaf(xv.w, gv.w, a[e]))));
    }
  }
#pragma unroll
  for (int off = 1; off < 64; off <<= 1)
#pragma unroll
    for (int e = 0; e < NE; e++) a[e] += __shfl_xor(a[e], off);
  if (lane == 0) {
    float s[NE], b[NE];
#pragma unroll
    for (int e = 0; e < NE; e++) {
      s[e] = 1.f / (1.f + expf(-a[e]));
      b[e] = s[e] + bias[e];
    }
    int e1 = 0; float v1 = b[0];
#pragma unroll
    for (int e = 1; e < NE; e++) if (b[e] > v1) { v1 = b[e]; e1 = e; }
    int e2 = -1; float v2 = -1e30f;
#pragma unroll
    for (int e = 0; e < NE; e++) if (e != e1 && b[e] > v2) { v2 = b[e]; e2 = e; }
    sel[t * 2] = e1; sel[t * 2 + 1] = e2;
    selscore[t * 2] = s[e1];       // ROUTE_SCALE == 1
    selscore[t * 2 + 1] = s[e2];
  }
}

// ---------------- rank: atomic-free permutation; 128-aligned segments --------
__global__ __launch_bounds__(1024) void rank_kernel(
    const int* __restrict__ sel, const float* __restrict__ selscore,
    int* __restrict__ slot2pos, float* __restrict__ slot_score,
    int* __restrict__ counts, int* __restrict__ offsets) {
  __shared__ int hist[NE * 1024];
  __shared__ int tot[NE];
  __shared__ int offs[NE];
  int tid = threadIdx.x;
  int sl[16];
  int h[NE];
#pragma unroll
  for (int e = 0; e < NE; e++) h[e] = 0;
#pragma unroll
  for (int j = 0; j < 4; j++) {
    int4 v = ((const int4*)sel)[tid * 4 + j];
    sl[j * 4 + 0] = v.x; sl[j * 4 + 1] = v.y;
    sl[j * 4 + 2] = v.z; sl[j * 4 + 3] = v.w;
  }
#pragma unroll
  for (int i = 0; i < 16; i++)
#pragma unroll
    for (int e = 0; e < NE; e++) h[e] += (sl[i] == e) ? 1 : 0;
#pragma unroll
  for (int e = 0; e < NE; e++) hist[e * 1024 + tid] = h[e];
  __syncthreads();
  int wid = tid >> 6, lane = tid & 63;
  if (wid < NE) {
    int e = wid;
    int vals[16];
    int lsum = 0;
#pragma unroll
    for (int i = 0; i < 16; i++) {
      int v = hist[e * 1024 + lane * 16 + i];
      vals[i] = lsum;
      lsum += v;
    }
    int incl = lsum;
#pragma unroll
    for (int off = 1; off < 64; off <<= 1) {
      int v = __shfl_up(incl, off);
      if (lane >= off) incl += v;
    }
    int excl = incl - lsum;
#pragma unroll
    for (int i = 0; i < 16; i++) hist[e * 1024 + lane * 16 + i] = vals[i] + excl;
    if (lane == 63) tot[e] = incl;
  }
  __syncthreads();
  if (tid == 0) {
    int acc = 0;
    for (int e = 0; e < NE; e++) {
      offs[e] = acc;
      offsets[e] = acc;
      counts[e] = tot[e];
      acc += (tot[e] + 127) & ~127;   // 128-align every segment
    }
  }
  __syncthreads();
  int base[NE];
#pragma unroll
  for (int e = 0; e < NE; e++) base[e] = offs[e] + hist[e * 1024 + tid];
#pragma unroll
  for (int i = 0; i < 16; i++) {
    int slot = tid * 16 + i;
    int e = sl[i];
    int pos = 0;
#pragma unroll
    for (int k = 0; k < NE; k++) pos += (e == k) ? base[k] : 0;
#pragma unroll
    for (int k = 0; k < NE; k++) base[k] += (e == k) ? 1 : 0;
    slot2pos[slot] = pos;
    slot_score[pos] = selscore[slot];
  }
}

// ---------------- gather: slot -> blocked row pos of bf16(s*x) ---------------
__global__ __launch_bounds__(256) void gather_kernel(
    const u16* __restrict__ xb, const float* __restrict__ selscore,
    const int* __restrict__ slot2pos, u16* __restrict__ routed) {
  int s = blockIdx.x * 4 + (threadIdx.x >> 6);
  int lane = threadIdx.x & 63;
  int pos = slot2pos[s];
  float sc = selscore[s];
  int t = s >> 1;
#pragma unroll
  for (int j = 0; j < 4; j++) {
    int c = j * 256 + lane * 4;
    uint2 v = *(const uint2*)&xb[ablk(t, c)];
    uint2 p;
    p.x = pack2(bflo(v.x) * sc, bfhi(v.x) * sc);
    p.y = pack2(bflo(v.y) * sc, bfhi(v.y) * sc);
    *(uint2*)&routed[ablk(pos, c)] = p;
  }
}

// ============================================================================
// Pipelined GEMM core (both GEMM kernels):
//  512 threads = 8 waves (wy2 x wn4), block tile 256 rows x 256 cols,
//  wave tile 128 rows x 64 cols (acc 4x2 f32x16 = 128 AGPR), mfma 32x32x16,
//  K-tile = 32. LDS: 3 buffers x 32 KB = 96 KB -> 1 block/CU, 2 waves/SIMD.
//  Per wave per K-tile: 12 ds_read_b128 feeding 16 MFMAs (0.75 KB/MFMA).
//  REGISTER BUDGET (R3 post-mortem): 512-thread blocks force <=256 regs/wave;
//  acc=128 AGPR leaves 128 arch VGPRs. R3 spilled (WRITE_SIZE +400 MB of
//  scratch). Fixes: (1) K-loop manually unrolled x3 so all LDS buffer bases
//  are compile-time constants; (2) staging pointers advance by constant
//  strides (no per-stage 64-bit mul); (3) compute streams A-frags (4-6 live
//  frags max). Counted-vmcnt distance-2 pipeline, 4 loads/wave/tile:
//    prologue: STAGE->b0, STAGE->b1                     [8 in flight]
//    iter t:   SYNC vmcnt(4)+barrier -> tile t resident, t+1 in flight
//              STAGE -> buffer of t-1 (reads done one barrier ago)
//              setprio(1); 16 MFMA; setprio(0)
//    tail:     SYNC(4); compute; SYNC(0); compute
// ============================================================================
#define BUFE 16384  // u16/buffer: A[half2][kc4][row128][8] | B[unit4][kc4][col64][8]

#define PIPE_STAGE(B)                                  \
  do {                                                 \
    u16* Lb = &lds[(B) * BUFE];                        \
    gload16(pA, Lb + adst);                            \
    gload16(pA2, Lb + 4096 + adst);                    \
    gload16(pBm, Lb + bdst);                           \
    gload16(pBm + 1024, Lb + 1024 + bdst);             \
    pA += 4096; pA2 += 4096; pBm += 2048;              \
  } while (0)

#define PIPE_COMPUTE(B)                                                  \
  do {                                                                   \
    _Pragma("unroll")                                                    \
    for (int c = 0; c < 2; c++) {                                        \
      int kc = 2 * c + l5;                                               \
      const u16* La = &lds[(B) * BUFE] + wy * 4096 + kc * 1024;          \
      const u16* Lw = &lds[(B) * BUFE] + 8192 + wn * 2048 + kc * 512;    \
      bf16x8 b0 = *(const bf16x8*)&Lw[l31 * 8];                          \
      bf16x8 b1 = *(const bf16x8*)&Lw[256 + l31 * 8];                    \
      bf16x8 a0 = *(const bf16x8*)&La[l31 * 8];                          \
      acc[0][0] = MFMA32(a0, b0, acc[0][0]);                             \
      acc[0][1] = MFMA32(a0, b1, acc[0][1]);                             \
      bf16x8 a1 = *(const bf16x8*)&La[256 + l31 * 8];                    \
      acc[1][0] = MFMA32(a1, b0, acc[1][0]);                             \
      acc[1][1] = MFMA32(a1, b1, acc[1][1]);                             \
      bf16x8 a2 = *(const bf16x8*)&La[512 + l31 * 8];                    \
      acc[2][0] = MFMA32(a2, b0, acc[2][0]);                             \
      acc[2][1] = MFMA32(a2, b1, acc[2][1]);                             \
      bf16x8 a3 = *(const bf16x8*)&La[768 + l31 * 8];                    \
      acc[3][0] = MFMA32(a3, b0, acc[3][0]);                             \
      acc[3][1] = MFMA32(a3, b1, acc[3][1]);                             \
    }                                                                    \
  } while (0)

#define PIPE_PHASE(SB, CB)                  \
  PIPE_SYNC(4);                             \
  PIPE_STAGE(SB);                           \
  __builtin_amdgcn_s_setprio(1);            \
  PIPE_COMPUTE(CB);                         \
  __builtin_amdgcn_s_setprio(0);

#define PIPE_LOOP()                         \
  PIPE_STAGE(0);                            \
  PIPE_STAGE(1);                            \
  _Pragma("unroll 1")                       \
  for (int t = 0; t < 30; t += 3) {         \
    PIPE_PHASE(2, 0);                       \
    PIPE_PHASE(0, 1);                       \
    PIPE_PHASE(1, 2);                       \
  }                                         \
  PIPE_SYNC(4);                             \
  __builtin_amdgcn_s_setprio(1);            \
  PIPE_COMPUTE(0);                          \
  __builtin_amdgcn_s_setprio(0);            \
  PIPE_SYNC(0);                             \
  __builtin_amdgcn_s_setprio(1);            \
  PIPE_COMPUTE(1);                          \
  __builtin_amdgcn_s_setprio(0);

// ---------------- dual GLU GEMM ---------------------------------------------
// Block covers 128 H-cols x both matrices. B units: u0=W1[0:64], u1=W1[64:128],
// u2=W3[0:64], u3=W3[64:128]. N-wave wn owns unit wn. Epilogue: two wy-rounds
// of f32 LDS exchange (128x128 = 64 KB); W3 waves write silu(h1)*h3.
__global__ __launch_bounds__(512) void dual_glu_gemm(
    const u16* __restrict__ A, const u16* __restrict__ W1,
    const u16* __restrict__ W3, u16* __restrict__ Hout,
    const u16* __restrict__ As, const u16* __restrict__ SW1,
    const u16* __restrict__ SW3, u16* __restrict__ Hs,
    const int* __restrict__ seg_off, const int* __restrict__ seg_cnt) {
  const int GX = 8, GY = 32, NWG = GX * GY * (NE + 1);
  int flat = blockIdx.x + GX * (blockIdx.y + GY * blockIdx.z);
  int swz = (flat & 7) * (NWG / 8) + (flat >> 3);   // bijective: NWG%8==0
  int bx = swz % GX;
  int rem = swz / GX;
  int by = rem % GY;
  int z = rem / GY;

  const u16 *Ap, *w1p, *w3p;
  u16* Hp;
  int soff, scnt;
  if (z < NE) {
    soff = seg_off[z]; scnt = seg_cnt[z];
    Ap = A;
    w1p = W1 + (size_t)z * HIDSZ * DIMSZ;
    w3p = W3 + (size_t)z * HIDSZ * DIMSZ;
    Hp = Hout;
  } else {
    soff = 0; scnt = T_TOK;
    Ap = As; w1p = SW1; w3p = SW3;
    Hp = Hs;
  }
  int mbase = by * 256;
  if (mbase >= scnt) return;
  int hx = bx;                               // 128-H-col tile

  __shared__ u16 lds[3 * BUFE];              // 96 KB

  int tid = threadIdx.x;
  int lane = tid & 63;
  int wid = tid >> 6;
  int wy = wid >> 2, wn = wid & 3;
  int l5 = lane >> 5, l31 = lane & 31;

  const u16* pA = Ap + (size_t)((soff + mbase) >> 7) * 32 * 4096 + tid * 8;
  const u16* pA2 = pA + 32 * 4096;
  int u = tid >> 7, iB = tid & 127;
  const u16* pBm = ((u < 2) ? w1p : w3p) +
                   (size_t)(hx * 2 + (u & 1)) * 32 * 2048 + iB * 8;
  int adst = tid * 8;
  int bdst = 8192 + u * 2048 + iB * 8;

  f32x16 acc[4][2];
#pragma unroll
  for (int i = 0; i < 4; i++) { acc[i][0] = (f32x16)0.f; acc[i][1] = (f32x16)0.f; }

  PIPE_LOOP();

  // ---- epilogue: two wy-rounds of f32 h1 exchange ----
  float* ex = (float*)lds;                   // 128 rows x 128 cols f32 = 64 KB
  for (int rr = 0; rr < 2; rr++) {
    __syncthreads();
    if (wy == rr && wn < 2) {
#pragma unroll
      for (int i = 0; i < 4; i++)
#pragma unroll
        for (int j = 0; j < 2; j++)
#pragma unroll
          for (int r = 0; r < 16; r++) {
            int rowl = i * 32 + (r & 3) + 8 * (r >> 2) + 4 * l5;
            ex[rowl * 128 + wn * 64 + j * 32 + l31] = acc[i][j][r];
          }
    }
    __syncthreads();
    if (wy == rr && wn >= 2) {
#pragma unroll
      for (int i = 0; i < 4; i++)
#pragma unroll
        for (int j = 0; j < 2; j++)
#pragma unroll
          for (int r = 0; r < 16; r++) {
            int rowl = i * 32 + (r & 3) + 8 * (r >> 2) + 4 * l5;
            int grow = mbase + rr * 128 + rowl;
            if (grow < scnt) {
              float h1 = ex[rowl * 128 + (wn - 2) * 64 + j * 32 + l31];
              Hp[ablk(soff + grow, hx * 128 + (wn - 2) * 64 + j * 32 + l31)] =
                  f2bf(silu_f(h1) * acc[i][j][r]);
            }
          }
    }
  }
}

// ---------------- GEMM2: Out = (A @ W^T) * scale -----------------------------
__global__ __launch_bounds__(512) void gemm2_kernel(
    const u16* __restrict__ A, const u16* __restrict__ W, u16* __restrict__ OutB,
    const u16* __restrict__ As, const u16* __restrict__ SW, float* __restrict__ OutF,
    const float* __restrict__ scale, const int* __restrict__ seg_off,
    const int* __restrict__ seg_cnt) {
  const int GX = 4, GY = 32, NWG = GX * GY * (NE + 1);
  int flat = blockIdx.x + GX * (blockIdx.y + GY * blockIdx.z);
  int swz = (flat & 7) * (NWG / 8) + (flat >> 3);
  int bx = swz % GX;
  int rem = swz / GX;
  int by = rem % GY;
  int z = rem / GY;

  const u16 *Ap, *wp;
  int soff, scnt;
  if (z < NE) {
    soff = seg_off[z]; scnt = seg_cnt[z];
    Ap = A; wp = W + (size_t)z * DIMSZ * HIDSZ;
  } else {
    soff = 0; scnt = T_TOK;
    Ap = As; wp = SW;
  }
  int mbase = by * 256;
  if (mbase >= scnt) return;
  int nbase = bx * 256;

  __shared__ u16 lds[3 * BUFE];

  int tid = threadIdx.x;
  int lane = tid & 63;
  int wid = tid >> 6;
  int wy = wid >> 2, wn = wid & 3;
  int l5 = lane >> 5, l31 = lane & 31;

  const u16* pA = Ap + (size_t)((soff + mbase) >> 7) * 32 * 4096 + tid * 8;
  const u16* pA2 = pA + 32 * 4096;
  int u = tid >> 7, iB = tid & 127;
  const u16* pBm = wp + (size_t)((nbase >> 6) + u) * 32 * 2048 + iB * 8;
  int adst = tid * 8;
  int bdst = 8192 + u * 2048 + iB * 8;

  f32x16 acc[4][2];
#pragma unroll
  for (int i = 0; i < 4; i++) { acc[i][0] = (f32x16)0.f; acc[i][1] = (f32x16)0.f; }

  PIPE_LOOP();

#pragma unroll
  for (int i = 0; i < 4; i++)
#pragma unroll
    for (int j = 0; j < 2; j++) {
      int colg = nbase + wn * 64 + j * 32 + l31;
#pragma unroll
      for (int r = 0; r < 16; r++) {
        int rowl = (r & 3) + 8 * (r >> 2) + 4 * l5;
        int grow = mbase + wy * 128 + i * 32 + rowl;
        if (grow < scnt) {
          size_t idx = (size_t)(soff + grow) * DIMSZ + colg;
          if (z < NE) {
            OutB[idx] = f2bf(acc[i][j][r] * scale[soff + grow]);
          } else {
            OutF[idx] = acc[i][j][r];
          }
        }
      }
    }
}

// ---------------- combine: out[t] += Or[pos(t,0)] + Or[pos(t,1)] -------------
__global__ __launch_bounds__(256) void combine_kernel(
    float* __restrict__ out, const u16* __restrict__ Orb,
    const int* __restrict__ slot2pos) {
  int t = blockIdx.x;
  int d = threadIdx.x * 4;
  int p0 = slot2pos[t * 2];
  int p1 = slot2pos[t * 2 + 1];
  float4 o = *(float4*)&out[(size_t)t * DIMSZ + d];
  uint2 a = *(const uint2*)&Orb[(size_t)p0 * DIMSZ + d];
  uint2 b = *(const uint2*)&Orb[(size_t)p1 * DIMSZ + d];
  o.x += bflo(a.x) + bflo(b.x);
  o.y += bfhi(a.x) + bfhi(b.x);
  o.z += bflo(a.y) + bflo(b.y);
  o.w += bfhi(a.y) + bfhi(b.y);
  *(float4*)&out[(size_t)t * DIMSZ + d] = o;
}

extern "C" void kernel_launch(void* const* d_in, const int* in_sizes, int n_in,
                              void* d_out, int out_size, void* d_ws, size_t ws_size,
                              hipStream_t stream) {
  const float* x = (const float*)d_in[0];
  const float* gw = (const float*)d_in[1];
  const float* w1 = (const float*)d_in[2];
  const float* w2 = (const float*)d_in[3];
  const float* w3 = (const float*)d_in[4];
  const float* sw1 = (const float*)d_in[5];
  const float* sw2 = (const float*)d_in[6];
  const float* sw3 = (const float*)d_in[7];
  const float* bias = (const float*)d_in[8];
  float* out = (float*)d_out;

  uint8_t* ws = (uint8_t*)d_ws;
  size_t off = 0;
  auto alloc = [&](size_t b) { size_t o = off; off += (b + 255) & ~(size_t)255; return o; };

  size_t ctrl = alloc(256);
  int* counts = (int*)(ws + ctrl);
  int* offsets = counts + 16;
  int* sel = (int*)(ws + alloc((size_t)NSLOT * 4));
  float* selscore = (float*)(ws + alloc((size_t)NSLOT * 4));
  float* slot_score = (float*)(ws + alloc((size_t)NPAD * 4));
  int* slot2pos = (int*)(ws + alloc((size_t)NSLOT * 4));
  u16* xb = (u16*)(ws + alloc((size_t)T_TOK * DIMSZ * 2));
  u16* routed = (u16*)(ws + alloc((size_t)NPAD * DIMSZ * 2));
  u16* Hbuf = (u16*)(ws + alloc((size_t)NPAD * HIDSZ * 2));
  u16* Orb = (u16*)(ws + alloc((size_t)NPAD * DIMSZ * 2));
  u16* Hs = (u16*)(ws + alloc((size_t)T_TOK * HIDSZ * 2));
  u16* w1b = (u16*)(ws + alloc((size_t)NE * HIDSZ * DIMSZ * 2));
  u16* w2b = (u16*)(ws + alloc((size_t)NE * DIMSZ * HIDSZ * 2));
  u16* w3b = (u16*)(ws + alloc((size_t)NE * HIDSZ * DIMSZ * 2));
  u16* sw1b = (u16*)(ws + alloc((size_t)HIDSZ * DIMSZ * 2));
  u16* sw2b = (u16*)(ws + alloc((size_t)DIMSZ * HIDSZ * 2));
  u16* sw3b = (u16*)(ws + alloc((size_t)HIDSZ * DIMSZ * 2));

  // weight conversion fp32 row-major -> bf16 blocked tiles (single launch)
  convert_blocked<<<dim3((NE + 1) * 16 * 32, 3), 256, 0, stream>>>(
      w1, w2, w3, sw1, sw2, sw3, w1b, w2b, w3b, sw1b, sw2b, sw3b);

  router_kernel<<<T_TOK / 4, 256, 0, stream>>>(x, gw, bias, sel, selscore, xb);
  rank_kernel<<<1, 1024, 0, stream>>>(sel, selscore, slot2pos, slot_score,
                                      counts, offsets);
  gather_kernel<<<NSLOT / 4, 256, 0, stream>>>(xb, selscore, slot2pos, routed);

  // unified GEMMs: z = 0..7 routed experts, z = 8 shared expert
  dual_glu_gemm<<<dim3(8, 32, NE + 1), 512, 0, stream>>>(
      routed, w1b, w3b, Hbuf, xb, sw1b, sw3b, Hs, offsets, counts);
  gemm2_kernel<<<dim3(4, 32, NE + 1), 512, 0, stream>>>(
      Hbuf, w2b, Orb, Hs, sw2b, out, slot_score, offsets, counts);

  // combine routed contributions into shared output
  combine_kernel<<<T_TOK, 256, 0, stream>>>(out, Orb, slot2pos);
}

// Round 5
// 707.960 us; speedup vs baseline: 1.9318x; 1.9318x over previous
//
#include <hip/hip_runtime.h>
#include <stdint.h>

typedef unsigned short u16;
typedef unsigned int u32;

#define T_TOK 8192      // B*S tokens
#define DIMSZ 1024
#define HIDSZ 1024
#define NE 8
#define NSLOT (T_TOK * 2)
#define NPAD (NSLOT + 1024)   // segment-aligned slot capacity
// NOTE: 256-row GEMM tiles may over-READ up to 255 rows past a segment's
// padded end; those reads land in the adjacent workspace buffer (benign,
// results masked on write). Keep workspace buffer order: routed->Hbuf->Orb.

typedef __attribute__((ext_vector_type(8))) __bf16 bf16x8;
typedef __attribute__((ext_vector_type(16))) float f32x16;

#define MFMA32(a, b, c) __builtin_amdgcn_mfma_f32_32x32x16_bf16(a, b, c, 0, 0, 0)

// ---- blocked tile layouts (all GEMM operands, K = 1024, KT = 32) ----------
// A (activations, 128-row tiles):  [mt][kt][kc][row(128)][8]  (8 KB / tile)
// W (weights, 64-row tiles):       [nt][kt][kc][col(64)][8]   (4 KB / tile)
__device__ __forceinline__ size_t ablk(int pos, int c) {
  return ((((size_t)(pos >> 7) * 32 + (c >> 5)) * 4 + ((c >> 3) & 3)) * 128 +
          (pos & 127)) * 8 + (c & 7);
}

__device__ __forceinline__ u16 f2bf(float f) {
  u32 u = __builtin_bit_cast(u32, f);
  u += 0x7FFFu + ((u >> 16) & 1u);   // RNE
  return (u16)(u >> 16);
}
__device__ __forceinline__ float bflo(u32 v) { return __builtin_bit_cast(float, v << 16); }
__device__ __forceinline__ float bfhi(u32 v) { return __builtin_bit_cast(float, v & 0xffff0000u); }
__device__ __forceinline__ u32 pack2(float a, float b) {
  return (u32)f2bf(a) | ((u32)f2bf(b) << 16);
}
__device__ __forceinline__ float silu_f(float v) { return v / (1.f + expf(-v)); }

// ---- async global->LDS, 16 B per lane (global_load_lds_dwordx4) -----------
__device__ __forceinline__ void gload16(const void* g, void* l) {
  __builtin_amdgcn_global_load_lds(
      (const __attribute__((address_space(1))) unsigned int*)g,
      (__attribute__((address_space(3))) unsigned int*)l, 16, 0, 0);
}

// counted-vmcnt barrier: wait until <=N of this wave's global_load_lds remain
// outstanding, then s_barrier (single asm so nothing schedules between).
#define PIPE_SYNC(N) asm volatile("s_waitcnt vmcnt(" #N ")\n\ts_barrier" ::: "memory")

// ---------------- weight convert: fp32 row-major -> bf16 blocked (1 launch) --
__global__ __launch_bounds__(256) void convert_blocked(
    const float* __restrict__ s0, const float* __restrict__ s1,
    const float* __restrict__ s2, const float* __restrict__ ss0,
    const float* __restrict__ ss1, const float* __restrict__ ss2,
    u16* __restrict__ d0, u16* __restrict__ d1, u16* __restrict__ d2,
    u16* __restrict__ ds0, u16* __restrict__ ds1, u16* __restrict__ ds2) {
  __shared__ u16 lt[2048];
  int t = blockIdx.x;
  const float* s;
  u16* d;
  if (t < NE * 16 * 32) {
    s = (blockIdx.y == 0) ? s0 : (blockIdx.y == 1) ? s1 : s2;
    d = (blockIdx.y == 0) ? d0 : (blockIdx.y == 1) ? d1 : d2;
  } else {
    t -= NE * 16 * 32;
    s = (blockIdx.y == 0) ? ss0 : (blockIdx.y == 1) ? ss1 : ss2;
    d = (blockIdx.y == 0) ? ds0 : (blockIdx.y == 1) ? ds1 : ds2;
  }
  int rt = t >> 5, kt = t & 31;           // 64-row group, k-tile
  const float* sp = s + (size_t)rt * 64 * 1024 + kt * 32;
  int nl = threadIdx.x >> 2, k0 = (threadIdx.x & 3) * 8;
  float4 a = *(const float4*)(sp + (size_t)nl * 1024 + k0);
  float4 b = *(const float4*)(sp + (size_t)nl * 1024 + k0 + 4);
  uint4 p;
  p.x = pack2(a.x, a.y); p.y = pack2(a.z, a.w);
  p.z = pack2(b.x, b.y); p.w = pack2(b.z, b.w);
  *(uint4*)&lt[(threadIdx.x & 3) * 512 + nl * 8] = p;   // [kc][col][8]
  __syncthreads();
  *(uint4*)(d + (size_t)t * 2048 + threadIdx.x * 8) = *(const uint4*)&lt[threadIdx.x * 8];
}

// ---------------- router: fp32 scores, top-2; emits blocked bf16(x) ----------
__global__ __launch_bounds__(256) void router_kernel(
    const float* __restrict__ x, const float* __restrict__ gw,
    const float* __restrict__ bias, int* __restrict__ sel,
    float* __restrict__ selscore, u16* __restrict__ xb) {
  int t = blockIdx.x * 4 + (threadIdx.x >> 6);
  int lane = threadIdx.x & 63;
  float a[NE];
#pragma unroll
  for (int e = 0; e < NE; e++) a[e] = 0.f;
#pragma unroll
  for (int j = 0; j < 4; j++) {
    int c = j * 256 + lane * 4;
    float4 xv = *(const float4*)&x[(size_t)t * DIMSZ + c];
    uint2 p;
    p.x = pack2(xv.x, xv.y);
    p.y = pack2(xv.z, xv.w);
    *(uint2*)&xb[ablk(t, c)] = p;
#pragma unroll
    for (int e = 0; e < NE; e++) {
      float4 gv = *(const float4*)&gw[e * DIMSZ + c];
      a[e] = fmaf(xv.x, gv.x, fmaf(xv.y, gv.y, fmaf(xv.z, gv.z, fmaf(xv.w, gv.w, a[e]))));
    }
  }
#pragma unroll
  for (int off = 1; off < 64; off <<= 1)
#pragma unroll
    for (int e = 0; e < NE; e++) a[e] += __shfl_xor(a[e], off);
  if (lane == 0) {
    float s[NE], b[NE];
#pragma unroll
    for (int e = 0; e < NE; e++) {
      s[e] = 1.f / (1.f + expf(-a[e]));
      b[e] = s[e] + bias[e];
    }
    int e1 = 0; float v1 = b[0];
#pragma unroll
    for (int e = 1; e < NE; e++) if (b[e] > v1) { v1 = b[e]; e1 = e; }
    int e2 = -1; float v2 = -1e30f;
#pragma unroll
    for (int e = 0; e < NE; e++) if (e != e1 && b[e] > v2) { v2 = b[e]; e2 = e; }
    sel[t * 2] = e1; sel[t * 2 + 1] = e2;
    selscore[t * 2] = s[e1];       // ROUTE_SCALE == 1
    selscore[t * 2 + 1] = s[e2];
  }
}

// ---------------- rank: atomic-free permutation; 128-aligned segments --------
__global__ __launch_bounds__(1024) void rank_kernel(
    const int* __restrict__ sel, const float* __restrict__ selscore,
    int* __restrict__ slot2pos, float* __restrict__ slot_score,
    int* __restrict__ counts, int* __restrict__ offsets) {
  __shared__ int hist[NE * 1024];
  __shared__ int tot[NE];
  __shared__ int offs[NE];
  int tid = threadIdx.x;
  int sl[16];
  int h[NE];
#pragma unroll
  for (int e = 0; e < NE; e++) h[e] = 0;
#pragma unroll
  for (int j = 0; j < 4; j++) {
    int4 v = ((const int4*)sel)[tid * 4 + j];
    sl[j * 4 + 0] = v.x; sl[j * 4 + 1] = v.y;
    sl[j * 4 + 2] = v.z; sl[j * 4 + 3] = v.w;
  }
#pragma unroll
  for (int i = 0; i < 16; i++)
#pragma unroll
    for (int e = 0; e < NE; e++) h[e] += (sl[i] == e) ? 1 : 0;
#pragma unroll
  for (int e = 0; e < NE; e++) hist[e * 1024 + tid] = h[e];
  __syncthreads();
  int wid = tid >> 6, lane = tid & 63;
  if (wid < NE) {
    int e = wid;
    int vals[16];
    int lsum = 0;
#pragma unroll
    for (int i = 0; i < 16; i++) {
      int v = hist[e * 1024 + lane * 16 + i];
      vals[i] = lsum;
      lsum += v;
    }
    int incl = lsum;
#pragma unroll
    for (int off = 1; off < 64; off <<= 1) {
      int v = __shfl_up(incl, off);
      if (lane >= off) incl += v;
    }
    int excl = incl - lsum;
#pragma unroll
    for (int i = 0; i < 16; i++) hist[e * 1024 + lane * 16 + i] = vals[i] + excl;
    if (lane == 63) tot[e] = incl;
  }
  __syncthreads();
  if (tid == 0) {
    int acc = 0;
    for (int e = 0; e < NE; e++) {
      offs[e] = acc;
      offsets[e] = acc;
      counts[e] = tot[e];
      acc += (tot[e] + 127) & ~127;   // 128-align every segment
    }
  }
  __syncthreads();
  int base[NE];
#pragma unroll
  for (int e = 0; e < NE; e++) base[e] = offs[e] + hist[e * 1024 + tid];
#pragma unroll
  for (int i = 0; i < 16; i++) {
    int slot = tid * 16 + i;
    int e = sl[i];
    int pos = 0;
#pragma unroll
    for (int k = 0; k < NE; k++) pos += (e == k) ? base[k] : 0;
#pragma unroll
    for (int k = 0; k < NE; k++) base[k] += (e == k) ? 1 : 0;
    slot2pos[slot] = pos;
    slot_score[pos] = selscore[slot];
  }
}

// ---------------- gather: slot -> blocked row pos of bf16(s*x) ---------------
__global__ __launch_bounds__(256) void gather_kernel(
    const u16* __restrict__ xb, const float* __restrict__ selscore,
    const int* __restrict__ slot2pos, u16* __restrict__ routed) {
  int s = blockIdx.x * 4 + (threadIdx.x >> 6);
  int lane = threadIdx.x & 63;
  int pos = slot2pos[s];
  float sc = selscore[s];
  int t = s >> 1;
#pragma unroll
  for (int j = 0; j < 4; j++) {
    int c = j * 256 + lane * 4;
    uint2 v = *(const uint2*)&xb[ablk(t, c)];
    uint2 p;
    p.x = pack2(bflo(v.x) * sc, bfhi(v.x) * sc);
    p.y = pack2(bflo(v.y) * sc, bfhi(v.y) * sc);
    *(uint2*)&routed[ablk(pos, c)] = p;
  }
}

// ============================================================================
// Pipelined GEMM core (both GEMM kernels):
//  256 threads = 4 waves (wy2 x wn2), block tile 256 rows x 128 cols,
//  wave tile 128 rows x 64 cols (acc 4x2 f32x16 = 128 acc regs), mfma
//  32x32x16, K-tile = 32. LDS: 3 buffers x 24 KB = 72 KB -> 2 blocks/CU
//  (144 <= 160), 8 waves/CU = 2/SIMD, register cap 256/wave.
//  REGISTER BUDGET (R3/R4 post-mortem): 512-thread blocks got a 128-reg/wave
//  budget from the compiler -> acc alone spilled (~400 MB scratch stores,
//  WRITE_SIZE 450 MB). 256-thread blocks with this exact wave tile allocated
//  cleanly in R1 (96 arch VGPR + acc in AGPRs, WRITE_SIZE normal).
//  Per wave per K-tile: 12 ds_read_b128 feeding 16 MFMAs (0.75 KB/MFMA).
//  Per CU per K-tile (2 blocks): 128 MFMA ~1033 cy vs 96 KB LDS reads
//  ~375 cy vs 48 KB stage ~190 cy -> matrix pipe is the long pole.
//  Counted-vmcnt distance-2 pipeline, 6 loads/wave/tile:
//    prologue: STAGE->b0, STAGE->b1                     [12 in flight]
//    iter t:   SYNC vmcnt(6)+barrier -> tile t resident, t+1 in flight
//              STAGE -> buffer of t-1 (reads done one barrier ago)
//              setprio(1); 16 MFMA; setprio(0)
//    tail:     SYNC(6); compute; SYNC(0); compute
// ============================================================================
#define BUFE 12288  // u16/buffer: A[half2][kc4][row128][8] | B[unit2][kc4][col64][8]

#define PIPE_STAGE(B)                                  \
  do {                                                 \
    u16* Lb = &lds[(B) * BUFE];                        \
    gload16(pAa, Lb + tid * 8);                        \
    gload16(pAa + 2048, Lb + 2048 + tid * 8);          \
    gload16(pAb, Lb + 4096 + tid * 8);                 \
    gload16(pAb + 2048, Lb + 6144 + tid * 8);          \
    gload16(pBu0, Lb + 8192 + tid * 8);                \
    gload16(pBu1, Lb + 10240 + tid * 8);               \
    pAa += 4096; pAb += 4096; pBu0 += 2048; pBu1 += 2048; \
  } while (0)

#define PIPE_COMPUTE(B)                                                  \
  do {                                                                   \
    _Pragma("unroll")                                                    \
    for (int c = 0; c < 2; c++) {                                        \
      int kc = 2 * c + l5;                                               \
      const u16* La = &lds[(B) * BUFE] + wy * 4096 + kc * 1024;          \
      const u16* Lw = &lds[(B) * BUFE] + 8192 + wn * 2048 + kc * 512;    \
      bf16x8 b0 = *(const bf16x8*)&Lw[l31 * 8];                          \
      bf16x8 b1 = *(const bf16x8*)&Lw[256 + l31 * 8];                    \
      bf16x8 a0 = *(const bf16x8*)&La[l31 * 8];                          \
      acc[0][0] = MFMA32(a0, b0, acc[0][0]);                             \
      acc[0][1] = MFMA32(a0, b1, acc[0][1]);                             \
      bf16x8 a1 = *(const bf16x8*)&La[256 + l31 * 8];                    \
      acc[1][0] = MFMA32(a1, b0, acc[1][0]);                             \
      acc[1][1] = MFMA32(a1, b1, acc[1][1]);                             \
      bf16x8 a2 = *(const bf16x8*)&La[512 + l31 * 8];                    \
      acc[2][0] = MFMA32(a2, b0, acc[2][0]);                             \
      acc[2][1] = MFMA32(a2, b1, acc[2][1]);                             \
      bf16x8 a3 = *(const bf16x8*)&La[768 + l31 * 8];                    \
      acc[3][0] = MFMA32(a3, b0, acc[3][0]);                             \
      acc[3][1] = MFMA32(a3, b1, acc[3][1]);                             \
    }                                                                    \
  } while (0)

#define PIPE_PHASE(SB, CB)                  \
  PIPE_SYNC(6);                             \
  PIPE_STAGE(SB);                           \
  __builtin_amdgcn_s_setprio(1);            \
  PIPE_COMPUTE(CB);                         \
  __builtin_amdgcn_s_setprio(0);

#define PIPE_LOOP()                         \
  PIPE_STAGE(0);                            \
  PIPE_STAGE(1);                            \
  _Pragma("unroll 1")                       \
  for (int t = 0; t < 30; t += 3) {         \
    PIPE_PHASE(2, 0);                       \
    PIPE_PHASE(0, 1);                       \
    PIPE_PHASE(1, 2);                       \
  }                                         \
  PIPE_SYNC(6);                             \
  __builtin_amdgcn_s_setprio(1);            \
  PIPE_COMPUTE(0);                          \
  __builtin_amdgcn_s_setprio(0);            \
  PIPE_SYNC(0);                             \
  __builtin_amdgcn_s_setprio(1);            \
  PIPE_COMPUTE(1);                          \
  __builtin_amdgcn_s_setprio(0);

// ---------------- dual GLU GEMM ---------------------------------------------
// Block covers 64 H-cols x both matrices. B units: u0 = W1[hx*64..+64],
// u1 = W3[same]. Wave wn owns unit wn. Epilogue: one f32 LDS exchange
// (256x64 = 64 KB); W3 waves write silu(h1)*h3.
__global__ __launch_bounds__(256, 2) void dual_glu_gemm(
    const u16* __restrict__ A, const u16* __restrict__ W1,
    const u16* __restrict__ W3, u16* __restrict__ Hout,
    const u16* __restrict__ As, const u16* __restrict__ SW1,
    const u16* __restrict__ SW3, u16* __restrict__ Hs,
    const int* __restrict__ seg_off, const int* __restrict__ seg_cnt) {
  const int GX = 16, GY = 32, NWG = GX * GY * (NE + 1);
  int flat = blockIdx.x + GX * (blockIdx.y + GY * blockIdx.z);
  int swz = (flat & 7) * (NWG / 8) + (flat >> 3);   // bijective: NWG%8==0
  int bx = swz % GX;
  int rem = swz / GX;
  int by = rem % GY;
  int z = rem / GY;

  const u16 *Ap, *w1p, *w3p;
  u16* Hp;
  int soff, scnt;
  if (z < NE) {
    soff = seg_off[z]; scnt = seg_cnt[z];
    Ap = A;
    w1p = W1 + (size_t)z * HIDSZ * DIMSZ;
    w3p = W3 + (size_t)z * HIDSZ * DIMSZ;
    Hp = Hout;
  } else {
    soff = 0; scnt = T_TOK;
    Ap = As; w1p = SW1; w3p = SW3;
    Hp = Hs;
  }
  int mbase = by * 256;
  if (mbase >= scnt) return;
  int hx = bx;                               // 64-H-col tile

  __shared__ u16 lds[3 * BUFE];              // 72 KB

  int tid = threadIdx.x;
  int lane = tid & 63;
  int wid = tid >> 6;
  int wy = wid >> 1, wn = wid & 1;
  int l5 = lane >> 5, l31 = lane & 31;

  const u16* pAa = Ap + (size_t)((soff + mbase) >> 7) * 32 * 4096 + tid * 8;
  const u16* pAb = pAa + 32 * 4096;
  const u16* pBu0 = w1p + (size_t)hx * 32 * 2048 + tid * 8;
  const u16* pBu1 = w3p + (size_t)hx * 32 * 2048 + tid * 8;

  f32x16 acc[4][2];
#pragma unroll
  for (int i = 0; i < 4; i++) { acc[i][0] = (f32x16)0.f; acc[i][1] = (f32x16)0.f; }

  PIPE_LOOP();

  // ---- epilogue: f32 h1 exchange (wn0 -> wn1), write silu(h1)*h3 ----
  __syncthreads();
  float* ex = (float*)lds;                   // 256 rows x 64 cols f32 = 64 KB
  if (wn == 0) {
#pragma unroll
    for (int i = 0; i < 4; i++)
#pragma unroll
      for (int j = 0; j < 2; j++)
#pragma unroll
        for (int r = 0; r < 16; r++) {
          int rowl = i * 32 + (r & 3) + 8 * (r >> 2) + 4 * l5;
          ex[(wy * 128 + rowl) * 64 + j * 32 + l31] = acc[i][j][r];
        }
  }
  __syncthreads();
  if (wn == 1) {
#pragma unroll
    for (int i = 0; i < 4; i++)
#pragma unroll
      for (int j = 0; j < 2; j++)
#pragma unroll
        for (int r = 0; r < 16; r++) {
          int rowl = i * 32 + (r & 3) + 8 * (r >> 2) + 4 * l5;
          int grow = mbase + wy * 128 + rowl;
          if (grow < scnt) {
            float h1 = ex[(wy * 128 + rowl) * 64 + j * 32 + l31];
            Hp[ablk(soff + grow, hx * 64 + j * 32 + l31)] =
                f2bf(silu_f(h1) * acc[i][j][r]);
          }
        }
  }
}

// ---------------- GEMM2: Out = (A @ W^T) * scale -----------------------------
__global__ __launch_bounds__(256, 2) void gemm2_kernel(
    const u16* __restrict__ A, const u16* __restrict__ W, u16* __restrict__ OutB,
    const u16* __restrict__ As, const u16* __restrict__ SW, float* __restrict__ OutF,
    const float* __restrict__ scale, const int* __restrict__ seg_off,
    const int* __restrict__ seg_cnt) {
  const int GX = 8, GY = 32, NWG = GX * GY * (NE + 1);
  int flat = blockIdx.x + GX * (blockIdx.y + GY * blockIdx.z);
  int swz = (flat & 7) * (NWG / 8) + (flat >> 3);
  int bx = swz % GX;
  int rem = swz / GX;
  int by = rem % GY;
  int z = rem / GY;

  const u16 *Ap, *wp;
  int soff, scnt;
  if (z < NE) {
    soff = seg_off[z]; scnt = seg_cnt[z];
    Ap = A; wp = W + (size_t)z * DIMSZ * HIDSZ;
  } else {
    soff = 0; scnt = T_TOK;
    Ap = As; wp = SW;
  }
  int mbase = by * 256;
  if (mbase >= scnt) return;
  int nbase = bx * 128;

  __shared__ u16 lds[3 * BUFE];

  int tid = threadIdx.x;
  int lane = tid & 63;
  int wid = tid >> 6;
  int wy = wid >> 1, wn = wid & 1;
  int l5 = lane >> 5, l31 = lane & 31;

  const u16* pAa = Ap + (size_t)((soff + mbase) >> 7) * 32 * 4096 + tid * 8;
  const u16* pAb = pAa + 32 * 4096;
  const u16* pBu0 = wp + (size_t)(nbase >> 6) * 32 * 2048 + tid * 8;
  const u16* pBu1 = pBu0 + 32 * 2048;

  f32x16 acc[4][2];
#pragma unroll
  for (int i = 0; i < 4; i++) { acc[i][0] = (f32x16)0.f; acc[i][1] = (f32x16)0.f; }

  PIPE_LOOP();

#pragma unroll
  for (int i = 0; i < 4; i++)
#pragma unroll
    for (int j = 0; j < 2; j++) {
      int colg = nbase + wn * 64 + j * 32 + l31;
#pragma unroll
      for (int r = 0; r < 16; r++) {
        int rowl = (r & 3) + 8 * (r >> 2) + 4 * l5;
        int grow = mbase + wy * 128 + i * 32 + rowl;
        if (grow < scnt) {
          size_t idx = (size_t)(soff + grow) * DIMSZ + colg;
          if (z < NE) {
            OutB[idx] = f2bf(acc[i][j][r] * scale[soff + grow]);
          } else {
            OutF[idx] = acc[i][j][r];
          }
        }
      }
    }
}

// ---------------- combine: out[t] += Or[pos(t,0)] + Or[pos(t,1)] -------------
__global__ __launch_bounds__(256) void combine_kernel(
    float* __restrict__ out, const u16* __restrict__ Orb,
    const int* __restrict__ slot2pos) {
  int t = blockIdx.x;
  int d = threadIdx.x * 4;
  int p0 = slot2pos[t * 2];
  int p1 = slot2pos[t * 2 + 1];
  float4 o = *(float4*)&out[(size_t)t * DIMSZ + d];
  uint2 a = *(const uint2*)&Orb[(size_t)p0 * DIMSZ + d];
  uint2 b = *(const uint2*)&Orb[(size_t)p1 * DIMSZ + d];
  o.x += bflo(a.x) + bflo(b.x);
  o.y += bfhi(a.x) + bfhi(b.x);
  o.z += bflo(a.y) + bflo(b.y);
  o.w += bfhi(a.y) + bfhi(b.y);
  *(float4*)&out[(size_t)t * DIMSZ + d] = o;
}

extern "C" void kernel_launch(void* const* d_in, const int* in_sizes, int n_in,
                              void* d_out, int out_size, void* d_ws, size_t ws_size,
                              hipStream_t stream) {
  const float* x = (const float*)d_in[0];
  const float* gw = (const float*)d_in[1];
  const float* w1 = (const float*)d_in[2];
  const float* w2 = (const float*)d_in[3];
  const float* w3 = (const float*)d_in[4];
  const float* sw1 = (const float*)d_in[5];
  const float* sw2 = (const float*)d_in[6];
  const float* sw3 = (const float*)d_in[7];
  const float* bias = (const float*)d_in[8];
  float* out = (float*)d_out;

  uint8_t* ws = (uint8_t*)d_ws;
  size_t off = 0;
  auto alloc = [&](size_t b) { size_t o = off; off += (b + 255) & ~(size_t)255; return o; };

  size_t ctrl = alloc(256);
  int* counts = (int*)(ws + ctrl);
  int* offsets = counts + 16;
  int* sel = (int*)(ws + alloc((size_t)NSLOT * 4));
  float* selscore = (float*)(ws + alloc((size_t)NSLOT * 4));
  float* slot_score = (float*)(ws + alloc((size_t)NPAD * 4));
  int* slot2pos = (int*)(ws + alloc((size_t)NSLOT * 4));
  u16* xb = (u16*)(ws + alloc((size_t)T_TOK * DIMSZ * 2));
  u16* routed = (u16*)(ws + alloc((size_t)NPAD * DIMSZ * 2));
  u16* Hbuf = (u16*)(ws + alloc((size_t)NPAD * HIDSZ * 2));
  u16* Orb = (u16*)(ws + alloc((size_t)NPAD * DIMSZ * 2));
  u16* Hs = (u16*)(ws + alloc((size_t)T_TOK * HIDSZ * 2));
  u16* w1b = (u16*)(ws + alloc((size_t)NE * HIDSZ * DIMSZ * 2));
  u16* w2b = (u16*)(ws + alloc((size_t)NE * DIMSZ * HIDSZ * 2));
  u16* w3b = (u16*)(ws + alloc((size_t)NE * HIDSZ * DIMSZ * 2));
  u16* sw1b = (u16*)(ws + alloc((size_t)HIDSZ * DIMSZ * 2));
  u16* sw2b = (u16*)(ws + alloc((size_t)DIMSZ * HIDSZ * 2));
  u16* sw3b = (u16*)(ws + alloc((size_t)HIDSZ * DIMSZ * 2));

  // weight conversion fp32 row-major -> bf16 blocked tiles (single launch)
  convert_blocked<<<dim3((NE + 1) * 16 * 32, 3), 256, 0, stream>>>(
      w1, w2, w3, sw1, sw2, sw3, w1b, w2b, w3b, sw1b, sw2b, sw3b);

  router_kernel<<<T_TOK / 4, 256, 0, stream>>>(x, gw, bias, sel, selscore, xb);
  rank_kernel<<<1, 1024, 0, stream>>>(sel, selscore, slot2pos, slot_score,
                                      counts, offsets);
  gather_kernel<<<NSLOT / 4, 256, 0, stream>>>(xb, selscore, slot2pos, routed);

  // unified GEMMs: z = 0..7 routed experts, z = 8 shared expert
  dual_glu_gemm<<<dim3(16, 32, NE + 1), 256, 0, stream>>>(
      routed, w1b, w3b, Hbuf, xb, sw1b, sw3b, Hs, offsets, counts);
  gemm2_kernel<<<dim3(8, 32, NE + 1), 256, 0, stream>>>(
      Hbuf, w2b, Orb, Hs, sw2b, out, slot_score, offsets, counts);

  // combine routed contributions into shared output
  combine_kernel<<<T_TOK, 256, 0, stream>>>(out, Orb, slot2pos);
}

// Round 6
// 595.561 us; speedup vs baseline: 2.2964x; 1.1887x over previous
//
#include <hip/hip_runtime.h>
#include <stdint.h>

typedef unsigned short u16;
typedef unsigned int u32;

#define T_TOK 8192      // B*S tokens
#define DIMSZ 1024
#define HIDSZ 1024
#define NE 8
#define NSLOT (T_TOK * 2)
#define NPAD (NSLOT + 1024)   // segment-aligned slot capacity
// NOTE: 256-row GEMM tiles may over-READ up to 255 rows past a segment's
// padded end; those reads land in the adjacent workspace buffer (benign,
// results masked on write). Keep workspace buffer order: routed->Hbuf->Orb.

typedef __attribute__((ext_vector_type(8))) __bf16 bf16x8;
typedef __attribute__((ext_vector_type(16))) float f32x16;

#define MFMA32(a, b, c) __builtin_amdgcn_mfma_f32_32x32x16_bf16(a, b, c, 0, 0, 0)

// ---- blocked tile layouts (all GEMM operands, K = 1024, KT = 32) ----------
// A (activations, 128-row tiles):  [mt][kt][kc][row(128)][8]  (8 KB / tile)
// W (weights, 64-row tiles):       [nt][kt][kc][col(64)][8]   (4 KB / tile)
__device__ __forceinline__ size_t ablk(int pos, int c) {
  return ((((size_t)(pos >> 7) * 32 + (c >> 5)) * 4 + ((c >> 3) & 3)) * 128 +
          (pos & 127)) * 8 + (c & 7);
}

__device__ __forceinline__ u16 f2bf(float f) {
  u32 u = __builtin_bit_cast(u32, f);
  u += 0x7FFFu + ((u >> 16) & 1u);   // RNE
  return (u16)(u >> 16);
}
__device__ __forceinline__ float bflo(u32 v) { return __builtin_bit_cast(float, v << 16); }
__device__ __forceinline__ float bfhi(u32 v) { return __builtin_bit_cast(float, v & 0xffff0000u); }
__device__ __forceinline__ u32 pack2(float a, float b) {
  return (u32)f2bf(a) | ((u32)f2bf(b) << 16);
}
__device__ __forceinline__ float silu_f(float v) { return v / (1.f + expf(-v)); }

// ---- async global->LDS, 16 B per lane (global_load_lds_dwordx4) -----------
__device__ __forceinline__ void gload16(const void* g, void* l) {
  __builtin_amdgcn_global_load_lds(
      (const __attribute__((address_space(1))) unsigned int*)g,
      (__attribute__((address_space(3))) unsigned int*)l, 16, 0, 0);
}

// counted-vmcnt barrier: wait until <=N of this wave's global_load_lds remain
// outstanding, then s_barrier (single asm so nothing schedules between).
#define PIPE_SYNC(N) asm volatile("s_waitcnt vmcnt(" #N ")\n\ts_barrier" ::: "memory")

// ---------------- weight convert: fp32 row-major -> bf16 blocked (1 launch) --
__global__ __launch_bounds__(256) void convert_blocked(
    const float* __restrict__ s0, const float* __restrict__ s1,
    const float* __restrict__ s2, const float* __restrict__ ss0,
    const float* __restrict__ ss1, const float* __restrict__ ss2,
    u16* __restrict__ d0, u16* __restrict__ d1, u16* __restrict__ d2,
    u16* __restrict__ ds0, u16* __restrict__ ds1, u16* __restrict__ ds2) {
  __shared__ u16 lt[2048];
  int t = blockIdx.x;
  const float* s;
  u16* d;
  if (t < NE * 16 * 32) {
    s = (blockIdx.y == 0) ? s0 : (blockIdx.y == 1) ? s1 : s2;
    d = (blockIdx.y == 0) ? d0 : (blockIdx.y == 1) ? d1 : d2;
  } else {
    t -= NE * 16 * 32;
    s = (blockIdx.y == 0) ? ss0 : (blockIdx.y == 1) ? ss1 : ss2;
    d = (blockIdx.y == 0) ? ds0 : (blockIdx.y == 1) ? ds1 : ds2;
  }
  int rt = t >> 5, kt = t & 31;           // 64-row group, k-tile
  const float* sp = s + (size_t)rt * 64 * 1024 + kt * 32;
  int nl = threadIdx.x >> 2, k0 = (threadIdx.x & 3) * 8;
  float4 a = *(const float4*)(sp + (size_t)nl * 1024 + k0);
  float4 b = *(const float4*)(sp + (size_t)nl * 1024 + k0 + 4);
  uint4 p;
  p.x = pack2(a.x, a.y); p.y = pack2(a.z, a.w);
  p.z = pack2(b.x, b.y); p.w = pack2(b.z, b.w);
  *(uint4*)&lt[(threadIdx.x & 3) * 512 + nl * 8] = p;   // [kc][col][8]
  __syncthreads();
  *(uint4*)(d + (size_t)t * 2048 + threadIdx.x * 8) = *(const uint4*)&lt[threadIdx.x * 8];
}

// ---------------- router: fp32 scores, top-2; emits blocked bf16(x) ----------
__global__ __launch_bounds__(256) void router_kernel(
    const float* __restrict__ x, const float* __restrict__ gw,
    const float* __restrict__ bias, int* __restrict__ sel,
    float* __restrict__ selscore, u16* __restrict__ xb) {
  int t = blockIdx.x * 4 + (threadIdx.x >> 6);
  int lane = threadIdx.x & 63;
  float a[NE];
#pragma unroll
  for (int e = 0; e < NE; e++) a[e] = 0.f;
#pragma unroll
  for (int j = 0; j < 4; j++) {
    int c = j * 256 + lane * 4;
    float4 xv = *(const float4*)&x[(size_t)t * DIMSZ + c];
    uint2 p;
    p.x = pack2(xv.x, xv.y);
    p.y = pack2(xv.z, xv.w);
    *(uint2*)&xb[ablk(t, c)] = p;
#pragma unroll
    for (int e = 0; e < NE; e++) {
      float4 gv = *(const float4*)&gw[e * DIMSZ + c];
      a[e] = fmaf(xv.x, gv.x, fmaf(xv.y, gv.y, fmaf(xv.z, gv.z, fmaf(xv.w, gv.w, a[e]))));
    }
  }
#pragma unroll
  for (int off = 1; off < 64; off <<= 1)
#pragma unroll
    for (int e = 0; e < NE; e++) a[e] += __shfl_xor(a[e], off);
  if (lane == 0) {
    float s[NE], b[NE];
#pragma unroll
    for (int e = 0; e < NE; e++) {
      s[e] = 1.f / (1.f + expf(-a[e]));
      b[e] = s[e] + bias[e];
    }
    int e1 = 0; float v1 = b[0];
#pragma unroll
    for (int e = 1; e < NE; e++) if (b[e] > v1) { v1 = b[e]; e1 = e; }
    int e2 = -1; float v2 = -1e30f;
#pragma unroll
    for (int e = 0; e < NE; e++) if (e != e1 && b[e] > v2) { v2 = b[e]; e2 = e; }
    sel[t * 2] = e1; sel[t * 2 + 1] = e2;
    selscore[t * 2] = s[e1];       // ROUTE_SCALE == 1
    selscore[t * 2 + 1] = s[e2];
  }
}

// ---------------- rank: atomic-free permutation; 128-aligned segments --------
__global__ __launch_bounds__(1024) void rank_kernel(
    const int* __restrict__ sel, const float* __restrict__ selscore,
    int* __restrict__ slot2pos, float* __restrict__ slot_score,
    int* __restrict__ counts, int* __restrict__ offsets) {
  __shared__ int hist[NE * 1024];
  __shared__ int tot[NE];
  __shared__ int offs[NE];
  int tid = threadIdx.x;
  int sl[16];
  int h[NE];
#pragma unroll
  for (int e = 0; e < NE; e++) h[e] = 0;
#pragma unroll
  for (int j = 0; j < 4; j++) {
    int4 v = ((const int4*)sel)[tid * 4 + j];
    sl[j * 4 + 0] = v.x; sl[j * 4 + 1] = v.y;
    sl[j * 4 + 2] = v.z; sl[j * 4 + 3] = v.w;
  }
#pragma unroll
  for (int i = 0; i < 16; i++)
#pragma unroll
    for (int e = 0; e < NE; e++) h[e] += (sl[i] == e) ? 1 : 0;
#pragma unroll
  for (int e = 0; e < NE; e++) hist[e * 1024 + tid] = h[e];
  __syncthreads();
  int wid = tid >> 6, lane = tid & 63;
  if (wid < NE) {
    int e = wid;
    int vals[16];
    int lsum = 0;
#pragma unroll
    for (int i = 0; i < 16; i++) {
      int v = hist[e * 1024 + lane * 16 + i];
      vals[i] = lsum;
      lsum += v;
    }
    int incl = lsum;
#pragma unroll
    for (int off = 1; off < 64; off <<= 1) {
      int v = __shfl_up(incl, off);
      if (lane >= off) incl += v;
    }
    int excl = incl - lsum;
#pragma unroll
    for (int i = 0; i < 16; i++) hist[e * 1024 + lane * 16 + i] = vals[i] + excl;
    if (lane == 63) tot[e] = incl;
  }
  __syncthreads();
  if (tid == 0) {
    int acc = 0;
    for (int e = 0; e < NE; e++) {
      offs[e] = acc;
      offsets[e] = acc;
      counts[e] = tot[e];
      acc += (tot[e] + 127) & ~127;   // 128-align every segment
    }
  }
  __syncthreads();
  int base[NE];
#pragma unroll
  for (int e = 0; e < NE; e++) base[e] = offs[e] + hist[e * 1024 + tid];
#pragma unroll
  for (int i = 0; i < 16; i++) {
    int slot = tid * 16 + i;
    int e = sl[i];
    int pos = 0;
#pragma unroll
    for (int k = 0; k < NE; k++) pos += (e == k) ? base[k] : 0;
#pragma unroll
    for (int k = 0; k < NE; k++) base[k] += (e == k) ? 1 : 0;
    slot2pos[slot] = pos;
    slot_score[pos] = selscore[slot];
  }
}

// ---------------- gather: slot -> blocked row pos of bf16(s*x) ---------------
__global__ __launch_bounds__(256) void gather_kernel(
    const u16* __restrict__ xb, const float* __restrict__ selscore,
    const int* __restrict__ slot2pos, u16* __restrict__ routed) {
  int s = blockIdx.x * 4 + (threadIdx.x >> 6);
  int lane = threadIdx.x & 63;
  int pos = slot2pos[s];
  float sc = selscore[s];
  int t = s >> 1;
#pragma unroll
  for (int j = 0; j < 4; j++) {
    int c = j * 256 + lane * 4;
    uint2 v = *(const uint2*)&xb[ablk(t, c)];
    uint2 p;
    p.x = pack2(bflo(v.x) * sc, bfhi(v.x) * sc);
    p.y = pack2(bflo(v.y) * sc, bfhi(v.y) * sc);
    *(uint2*)&routed[ablk(pos, c)] = p;
  }
}

// ============================================================================
// Pipelined GEMM core (both GEMM kernels): identical to R5 (verified pass,
// spill-free, FETCH near-ideal).
//  256 threads = 4 waves (wy2 x wn2), block tile 256 rows x 128 cols,
//  wave tile 128 rows x 64 cols (acc 4x2 f32x16), mfma 32x32x16, K-tile=32.
//  LDS 3 x 24 KB = 72 KB -> 2 blocks/CU. LDS-BW ceiling at 256 B/cy/CU:
//  MFMA 256 cy vs LDS 375 cy per CU-K-tile -> MfmaUtil ceiling ~68%
//  (vs 34% for the 64x32-wave-tile geometries R0/R2 -- both measured 34!).
//  Counted-vmcnt distance-2 pipeline, 6 loads/wave/tile (ledger in R5).
//
// R5 POST-MORTEM (the only change this round): the chunked XCD swizzle gave
// XCD7 the whole shared-expert block range (512 useful blocks) while others
// got ~146 -> device idled behind XCD7's tail (Occupancy 6.7%, MfmaUtil 12%).
// New mapping, balanced by construction (block-granularity round-robin
// xcd = flat % 8): XCD x owns logical chunks {z=x, by=0..31} U {z=8,
// by=4x..4x+4}; bijective; every XCD gets ~8 useful expert chunks (one
// expert's weights stay in its L2) + 4 shared chunks, shared chunks first.
// ============================================================================
#define BUFE 12288  // u16/buffer: A[half2][kc4][row128][8] | B[unit2][kc4][col64][8]

#define PIPE_STAGE(B)                                  \
  do {                                                 \
    u16* Lb = &lds[(B) * BUFE];                        \
    gload16(pAa, Lb + tid * 8);                        \
    gload16(pAa + 2048, Lb + 2048 + tid * 8);          \
    gload16(pAb, Lb + 4096 + tid * 8);                 \
    gload16(pAb + 2048, Lb + 6144 + tid * 8);          \
    gload16(pBu0, Lb + 8192 + tid * 8);                \
    gload16(pBu1, Lb + 10240 + tid * 8);               \
    pAa += 4096; pAb += 4096; pBu0 += 2048; pBu1 += 2048; \
  } while (0)

#define PIPE_COMPUTE(B)                                                  \
  do {                                                                   \
    _Pragma("unroll")                                                    \
    for (int c = 0; c < 2; c++) {                                        \
      int kc = 2 * c + l5;                                               \
      const u16* La = &lds[(B) * BUFE] + wy * 4096 + kc * 1024;          \
      const u16* Lw = &lds[(B) * BUFE] + 8192 + wn * 2048 + kc * 512;    \
      bf16x8 b0 = *(const bf16x8*)&Lw[l31 * 8];                          \
      bf16x8 b1 = *(const bf16x8*)&Lw[256 + l31 * 8];                    \
      bf16x8 a0 = *(const bf16x8*)&La[l31 * 8];                          \
      acc[0][0] = MFMA32(a0, b0, acc[0][0]);                             \
      acc[0][1] = MFMA32(a0, b1, acc[0][1]);                             \
      bf16x8 a1 = *(const bf16x8*)&La[256 + l31 * 8];                    \
      acc[1][0] = MFMA32(a1, b0, acc[1][0]);                             \
      acc[1][1] = MFMA32(a1, b1, acc[1][1]);                             \
      bf16x8 a2 = *(const bf16x8*)&La[512 + l31 * 8];                    \
      acc[2][0] = MFMA32(a2, b0, acc[2][0]);                             \
      acc[2][1] = MFMA32(a2, b1, acc[2][1]);                             \
      bf16x8 a3 = *(const bf16x8*)&La[768 + l31 * 8];                    \
      acc[3][0] = MFMA32(a3, b0, acc[3][0]);                             \
      acc[3][1] = MFMA32(a3, b1, acc[3][1]);                             \
    }                                                                    \
  } while (0)

#define PIPE_PHASE(SB, CB)                  \
  PIPE_SYNC(6);                             \
  PIPE_STAGE(SB);                           \
  __builtin_amdgcn_s_setprio(1);            \
  PIPE_COMPUTE(CB);                         \
  __builtin_amdgcn_s_setprio(0);

#define PIPE_LOOP()                         \
  PIPE_STAGE(0);                            \
  PIPE_STAGE(1);                            \
  _Pragma("unroll 1")                       \
  for (int t = 0; t < 30; t += 3) {         \
    PIPE_PHASE(2, 0);                       \
    PIPE_PHASE(0, 1);                       \
    PIPE_PHASE(1, 2);                       \
  }                                         \
  PIPE_SYNC(6);                             \
  __builtin_amdgcn_s_setprio(1);            \
  PIPE_COMPUTE(0);                          \
  __builtin_amdgcn_s_setprio(0);            \
  PIPE_SYNC(0);                             \
  __builtin_amdgcn_s_setprio(1);            \
  PIPE_COMPUTE(1);                          \
  __builtin_amdgcn_s_setprio(0);

// ---------------- dual GLU GEMM ---------------------------------------------
// Block covers 64 H-cols x both matrices. B units: u0 = W1[hx*64..+64],
// u1 = W3[same]. Wave wn owns unit wn. Epilogue: one f32 LDS exchange
// (256x64 = 64 KB); W3 waves write silu(h1)*h3.
__global__ __launch_bounds__(256, 2) void dual_glu_gemm(
    const u16* __restrict__ A, const u16* __restrict__ W1,
    const u16* __restrict__ W3, u16* __restrict__ Hout,
    const u16* __restrict__ As, const u16* __restrict__ SW1,
    const u16* __restrict__ SW3, u16* __restrict__ Hs,
    const int* __restrict__ seg_off, const int* __restrict__ seg_cnt) {
  // balanced XCD mapping (see header). GX=16, GY=32, GZ=9.
  int flat = blockIdx.x + 16 * blockIdx.y + 512 * blockIdx.z;
  int xcd = flat & 7;
  int r = flat >> 3;            // 0..575
  int bx = r & 15;
  int s = r >> 4;               // 0..35
  int z, by;
  if (s < 4) { z = NE; by = xcd * 4 + s; }       // shared-expert chunks first
  else       { z = xcd; by = s - 4; }

  const u16 *Ap, *w1p, *w3p;
  u16* Hp;
  int soff, scnt;
  if (z < NE) {
    soff = seg_off[z]; scnt = seg_cnt[z];
    Ap = A;
    w1p = W1 + (size_t)z * HIDSZ * DIMSZ;
    w3p = W3 + (size_t)z * HIDSZ * DIMSZ;
    Hp = Hout;
  } else {
    soff = 0; scnt = T_TOK;
    Ap = As; w1p = SW1; w3p = SW3;
    Hp = Hs;
  }
  int mbase = by * 256;
  if (mbase >= scnt) return;
  int hx = bx;                               // 64-H-col tile

  __shared__ u16 lds[3 * BUFE];              // 72 KB

  int tid = threadIdx.x;
  int lane = tid & 63;
  int wid = tid >> 6;
  int wy = wid >> 1, wn = wid & 1;
  int l5 = lane >> 5, l31 = lane & 31;

  const u16* pAa = Ap + (size_t)((soff + mbase) >> 7) * 32 * 4096 + tid * 8;
  const u16* pAb = pAa + 32 * 4096;
  const u16* pBu0 = w1p + (size_t)hx * 32 * 2048 + tid * 8;
  const u16* pBu1 = w3p + (size_t)hx * 32 * 2048 + tid * 8;

  f32x16 acc[4][2];
#pragma unroll
  for (int i = 0; i < 4; i++) { acc[i][0] = (f32x16)0.f; acc[i][1] = (f32x16)0.f; }

  PIPE_LOOP();

  // ---- epilogue: f32 h1 exchange (wn0 -> wn1), write silu(h1)*h3 ----
  __syncthreads();
  float* ex = (float*)lds;                   // 256 rows x 64 cols f32 = 64 KB
  if (wn == 0) {
#pragma unroll
    for (int i = 0; i < 4; i++)
#pragma unroll
      for (int j = 0; j < 2; j++)
#pragma unroll
        for (int r2 = 0; r2 < 16; r2++) {
          int rowl = i * 32 + (r2 & 3) + 8 * (r2 >> 2) + 4 * l5;
          ex[(wy * 128 + rowl) * 64 + j * 32 + l31] = acc[i][j][r2];
        }
  }
  __syncthreads();
  if (wn == 1) {
#pragma unroll
    for (int i = 0; i < 4; i++)
#pragma unroll
      for (int j = 0; j < 2; j++)
#pragma unroll
        for (int r2 = 0; r2 < 16; r2++) {
          int rowl = i * 32 + (r2 & 3) + 8 * (r2 >> 2) + 4 * l5;
          int grow = mbase + wy * 128 + rowl;
          if (grow < scnt) {
            float h1 = ex[(wy * 128 + rowl) * 64 + j * 32 + l31];
            Hp[ablk(soff + grow, hx * 64 + j * 32 + l31)] =
                f2bf(silu_f(h1) * acc[i][j][r2]);
          }
        }
  }
}

// ---------------- GEMM2: Out = (A @ W^T) * scale -----------------------------
__global__ __launch_bounds__(256, 2) void gemm2_kernel(
    const u16* __restrict__ A, const u16* __restrict__ W, u16* __restrict__ OutB,
    const u16* __restrict__ As, const u16* __restrict__ SW, float* __restrict__ OutF,
    const float* __restrict__ scale, const int* __restrict__ seg_off,
    const int* __restrict__ seg_cnt) {
  // balanced XCD mapping. GX=8, GY=32, GZ=9.
  int flat = blockIdx.x + 8 * blockIdx.y + 256 * blockIdx.z;
  int xcd = flat & 7;
  int r = flat >> 3;            // 0..287
  int bx = r & 7;
  int s = r >> 3;               // 0..35
  int z, by;
  if (s < 4) { z = NE; by = xcd * 4 + s; }
  else       { z = xcd; by = s - 4; }

  const u16 *Ap, *wp;
  int soff, scnt;
  if (z < NE) {
    soff = seg_off[z]; scnt = seg_cnt[z];
    Ap = A; wp = W + (size_t)z * DIMSZ * HIDSZ;
  } else {
    soff = 0; scnt = T_TOK;
    Ap = As; wp = SW;
  }
  int mbase = by * 256;
  if (mbase >= scnt) return;
  int nbase = bx * 128;

  __shared__ u16 lds[3 * BUFE];

  int tid = threadIdx.x;
  int lane = tid & 63;
  int wid = tid >> 6;
  int wy = wid >> 1, wn = wid & 1;
  int l5 = lane >> 5, l31 = lane & 31;

  const u16* pAa = Ap + (size_t)((soff + mbase) >> 7) * 32 * 4096 + tid * 8;
  const u16* pAb = pAa + 32 * 4096;
  const u16* pBu0 = wp + (size_t)(nbase >> 6) * 32 * 2048 + tid * 8;
  const u16* pBu1 = pBu0 + 32 * 2048;

  f32x16 acc[4][2];
#pragma unroll
  for (int i = 0; i < 4; i++) { acc[i][0] = (f32x16)0.f; acc[i][1] = (f32x16)0.f; }

  PIPE_LOOP();

#pragma unroll
  for (int i = 0; i < 4; i++)
#pragma unroll
    for (int j = 0; j < 2; j++) {
      int colg = nbase + wn * 64 + j * 32 + l31;
#pragma unroll
      for (int r2 = 0; r2 < 16; r2++) {
        int rowl = (r2 & 3) + 8 * (r2 >> 2) + 4 * l5;
        int grow = mbase + wy * 128 + i * 32 + rowl;
        if (grow < scnt) {
          size_t idx = (size_t)(soff + grow) * DIMSZ + colg;
          if (z < NE) {
            OutB[idx] = f2bf(acc[i][j][r2] * scale[soff + grow]);
          } else {
            OutF[idx] = acc[i][j][r2];
          }
        }
      }
    }
}

// ---------------- combine: out[t] += Or[pos(t,0)] + Or[pos(t,1)] -------------
__global__ __launch_bounds__(256) void combine_kernel(
    float* __restrict__ out, const u16* __restrict__ Orb,
    const int* __restrict__ slot2pos) {
  int t = blockIdx.x;
  int d = threadIdx.x * 4;
  int p0 = slot2pos[t * 2];
  int p1 = slot2pos[t * 2 + 1];
  float4 o = *(float4*)&out[(size_t)t * DIMSZ + d];
  uint2 a = *(const uint2*)&Orb[(size_t)p0 * DIMSZ + d];
  uint2 b = *(const uint2*)&Orb[(size_t)p1 * DIMSZ + d];
  o.x += bflo(a.x) + bflo(b.x);
  o.y += bfhi(a.x) + bfhi(b.x);
  o.z += bflo(a.y) + bflo(b.y);
  o.w += bfhi(a.y) + bfhi(b.y);
  *(float4*)&out[(size_t)t * DIMSZ + d] = o;
}

extern "C" void kernel_launch(void* const* d_in, const int* in_sizes, int n_in,
                              void* d_out, int out_size, void* d_ws, size_t ws_size,
                              hipStream_t stream) {
  const float* x = (const float*)d_in[0];
  const float* gw = (const float*)d_in[1];
  const float* w1 = (const float*)d_in[2];
  const float* w2 = (const float*)d_in[3];
  const float* w3 = (const float*)d_in[4];
  const float* sw1 = (const float*)d_in[5];
  const float* sw2 = (const float*)d_in[6];
  const float* sw3 = (const float*)d_in[7];
  const float* bias = (const float*)d_in[8];
  float* out = (float*)d_out;

  uint8_t* ws = (uint8_t*)d_ws;
  size_t off = 0;
  auto alloc = [&](size_t b) { size_t o = off; off += (b + 255) & ~(size_t)255; return o; };

  size_t ctrl = alloc(256);
  int* counts = (int*)(ws + ctrl);
  int* offsets = counts + 16;
  int* sel = (int*)(ws + alloc((size_t)NSLOT * 4));
  float* selscore = (float*)(ws + alloc((size_t)NSLOT * 4));
  float* slot_score = (float*)(ws + alloc((size_t)NPAD * 4));
  int* slot2pos = (int*)(ws + alloc((size_t)NSLOT * 4));
  u16* xb = (u16*)(ws + alloc((size_t)T_TOK * DIMSZ * 2));
  u16* routed = (u16*)(ws + alloc((size_t)NPAD * DIMSZ * 2));
  u16* Hbuf = (u16*)(ws + alloc((size_t)NPAD * HIDSZ * 2));
  u16* Orb = (u16*)(ws + alloc((size_t)NPAD * DIMSZ * 2));
  u16* Hs = (u16*)(ws + alloc((size_t)T_TOK * HIDSZ * 2));
  u16* w1b = (u16*)(ws + alloc((size_t)NE * HIDSZ * DIMSZ * 2));
  u16* w2b = (u16*)(ws + alloc((size_t)NE * DIMSZ * HIDSZ * 2));
  u16* w3b = (u16*)(ws + alloc((size_t)NE * HIDSZ * DIMSZ * 2));
  u16* sw1b = (u16*)(ws + alloc((size_t)HIDSZ * DIMSZ * 2));
  u16* sw2b = (u16*)(ws + alloc((size_t)DIMSZ * HIDSZ * 2));
  u16* sw3b = (u16*)(ws + alloc((size_t)HIDSZ * DIMSZ * 2));

  // weight conversion fp32 row-major -> bf16 blocked tiles (single launch)
  convert_blocked<<<dim3((NE + 1) * 16 * 32, 3), 256, 0, stream>>>(
      w1, w2, w3, sw1, sw2, sw3, w1b, w2b, w3b, sw1b, sw2b, sw3b);

  router_kernel<<<T_TOK / 4, 256, 0, stream>>>(x, gw, bias, sel, selscore, xb);
  rank_kernel<<<1, 1024, 0, stream>>>(sel, selscore, slot2pos, slot_score,
                                      counts, offsets);
  gather_kernel<<<NSLOT / 4, 256, 0, stream>>>(xb, selscore, slot2pos, routed);

  // unified GEMMs: z = 0..7 routed experts, z = 8 shared expert
  dual_glu_gemm<<<dim3(16, 32, NE + 1), 256, 0, stream>>>(
      routed, w1b, w3b, Hbuf, xb, sw1b, sw3b, Hs, offsets, counts);
  gemm2_kernel<<<dim3(8, 32, NE + 1), 256, 0, stream>>>(
      Hbuf, w2b, Orb, Hs, sw2b, out, slot_score, offsets, counts);

  // combine routed contributions into shared output
  combine_kernel<<<T_TOK, 256, 0, stream>>>(out, Orb, slot2pos);
}

// Round 8
// 486.466 us; speedup vs baseline: 2.8113x; 1.2243x over previous
//
#include <hip/hip_runtime.h>
#include <stdint.h>

typedef unsigned short u16;
typedef unsigned int u32;

#define T_TOK 8192      // B*S tokens
#define DIMSZ 1024
#define HIDSZ 1024
#define NE 8
#define NSLOT (T_TOK * 2)
#define NPAD (NSLOT + 1024)   // segment-aligned slot capacity
// NOTE: 256-row GEMM tiles may over-READ up to 255 rows past a segment's
// padded end; those reads land in the adjacent workspace buffer (benign,
// results masked on write). Keep workspace buffer order: routed->Hbuf->Orb.

typedef __attribute__((ext_vector_type(8))) __bf16 bf16x8;
typedef __attribute__((ext_vector_type(16))) float f32x16;

#define MFMA32(a, b, c) __builtin_amdgcn_mfma_f32_32x32x16_bf16(a, b, c, 0, 0, 0)

// ---- blocked tile layouts (all GEMM operands, K = 1024, KT = 32) ----------
// A (activations, 128-row tiles):  [mt][kt][kc][row(128)][8]  (8 KB / tile)
// W (weights, 64-row tiles):       [nt][kt][kc][col(64)][8]   (4 KB / tile)
__device__ __forceinline__ size_t ablk(int pos, int c) {
  return ((((size_t)(pos >> 7) * 32 + (c >> 5)) * 4 + ((c >> 3) & 3)) * 128 +
          (pos & 127)) * 8 + (c & 7);
}

__device__ __forceinline__ u16 f2bf(float f) {
  u32 u = __builtin_bit_cast(u32, f);
  u += 0x7FFFu + ((u >> 16) & 1u);   // RNE
  return (u16)(u >> 16);
}
__device__ __forceinline__ float bflo(u32 v) { return __builtin_bit_cast(float, v << 16); }
__device__ __forceinline__ float bfhi(u32 v) { return __builtin_bit_cast(float, v & 0xffff0000u); }
__device__ __forceinline__ u32 pack2(float a, float b) {
  return (u32)f2bf(a) | ((u32)f2bf(b) << 16);
}
__device__ __forceinline__ float silu_f(float v) { return v / (1.f + expf(-v)); }

// ---- async global->LDS, 16 B per lane (global_load_lds_dwordx4) -----------
__device__ __forceinline__ void gload16(const void* g, void* l) {
  __builtin_amdgcn_global_load_lds(
      (const __attribute__((address_space(1))) unsigned int*)g,
      (__attribute__((address_space(3))) unsigned int*)l, 16, 0, 0);
}

// counted-vmcnt barrier: wait until <=N of this wave's global_load_lds remain
// outstanding, then s_barrier (single asm so nothing schedules between).
#define PIPE_SYNC(N) asm volatile("s_waitcnt vmcnt(" #N ")\n\ts_barrier" ::: "memory")

// ---------------- weight convert: fp32 row-major -> bf16 blocked (1 launch) --
__global__ __launch_bounds__(256) void convert_blocked(
    const float* __restrict__ s0, const float* __restrict__ s1,
    const float* __restrict__ s2, const float* __restrict__ ss0,
    const float* __restrict__ ss1, const float* __restrict__ ss2,
    u16* __restrict__ d0, u16* __restrict__ d1, u16* __restrict__ d2,
    u16* __restrict__ ds0, u16* __restrict__ ds1, u16* __restrict__ ds2) {
  __shared__ u16 lt[2048];
  int t = blockIdx.x;
  const float* s;
  u16* d;
  if (t < NE * 16 * 32) {
    s = (blockIdx.y == 0) ? s0 : (blockIdx.y == 1) ? s1 : s2;
    d = (blockIdx.y == 0) ? d0 : (blockIdx.y == 1) ? d1 : d2;
  } else {
    t -= NE * 16 * 32;
    s = (blockIdx.y == 0) ? ss0 : (blockIdx.y == 1) ? ss1 : ss2;
    d = (blockIdx.y == 0) ? ds0 : (blockIdx.y == 1) ? ds1 : ds2;
  }
  int rt = t >> 5, kt = t & 31;           // 64-row group, k-tile
  const float* sp = s + (size_t)rt * 64 * 1024 + kt * 32;
  int nl = threadIdx.x >> 2, k0 = (threadIdx.x & 3) * 8;
  float4 a = *(const float4*)(sp + (size_t)nl * 1024 + k0);
  float4 b = *(const float4*)(sp + (size_t)nl * 1024 + k0 + 4);
  uint4 p;
  p.x = pack2(a.x, a.y); p.y = pack2(a.z, a.w);
  p.z = pack2(b.x, b.y); p.w = pack2(b.z, b.w);
  *(uint4*)&lt[(threadIdx.x & 3) * 512 + nl * 8] = p;   // [kc][col][8]
  __syncthreads();
  *(uint4*)(d + (size_t)t * 2048 + threadIdx.x * 8) = *(const uint4*)&lt[threadIdx.x * 8];
}

// ---------------- router: fp32 scores, top-2; emits blocked bf16(x) ----------
__global__ __launch_bounds__(256) void router_kernel(
    const float* __restrict__ x, const float* __restrict__ gw,
    const float* __restrict__ bias, int* __restrict__ sel,
    float* __restrict__ selscore, u16* __restrict__ xb) {
  int t = blockIdx.x * 4 + (threadIdx.x >> 6);
  int lane = threadIdx.x & 63;
  float a[NE];
#pragma unroll
  for (int e = 0; e < NE; e++) a[e] = 0.f;
#pragma unroll
  for (int j = 0; j < 4; j++) {
    int c = j * 256 + lane * 4;
    float4 xv = *(const float4*)&x[(size_t)t * DIMSZ + c];
    uint2 p;
    p.x = pack2(xv.x, xv.y);
    p.y = pack2(xv.z, xv.w);
    *(uint2*)&xb[ablk(t, c)] = p;
#pragma unroll
    for (int e = 0; e < NE; e++) {
      float4 gv = *(const float4*)&gw[e * DIMSZ + c];
      a[e] = fmaf(xv.x, gv.x, fmaf(xv.y, gv.y, fmaf(xv.z, gv.z, fmaf(xv.w, gv.w, a[e]))));
    }
  }
#pragma unroll
  for (int off = 1; off < 64; off <<= 1)
#pragma unroll
    for (int e = 0; e < NE; e++) a[e] += __shfl_xor(a[e], off);
  if (lane == 0) {
    float s[NE], b[NE];
#pragma unroll
    for (int e = 0; e < NE; e++) {
      s[e] = 1.f / (1.f + expf(-a[e]));
      b[e] = s[e] + bias[e];
    }
    int e1 = 0; float v1 = b[0];
#pragma unroll
    for (int e = 1; e < NE; e++) if (b[e] > v1) { v1 = b[e]; e1 = e; }
    int e2 = -1; float v2 = -1e30f;
#pragma unroll
    for (int e = 0; e < NE; e++) if (e != e1 && b[e] > v2) { v2 = b[e]; e2 = e; }
    sel[t * 2] = e1; sel[t * 2 + 1] = e2;
    selscore[t * 2] = s[e1];       // ROUTE_SCALE == 1
    selscore[t * 2 + 1] = s[e2];
  }
}

// ---------------- rank: atomic-free permutation; 128-aligned segments --------
__global__ __launch_bounds__(1024) void rank_kernel(
    const int* __restrict__ sel, const float* __restrict__ selscore,
    int* __restrict__ slot2pos, float* __restrict__ slot_score,
    int* __restrict__ counts, int* __restrict__ offsets) {
  __shared__ int hist[NE * 1024];
  __shared__ int tot[NE];
  __shared__ int offs[NE];
  int tid = threadIdx.x;
  int sl[16];
  int h[NE];
#pragma unroll
  for (int e = 0; e < NE; e++) h[e] = 0;
#pragma unroll
  for (int j = 0; j < 4; j++) {
    int4 v = ((const int4*)sel)[tid * 4 + j];
    sl[j * 4 + 0] = v.x; sl[j * 4 + 1] = v.y;
    sl[j * 4 + 2] = v.z; sl[j * 4 + 3] = v.w;
  }
#pragma unroll
  for (int i = 0; i < 16; i++)
#pragma unroll
    for (int e = 0; e < NE; e++) h[e] += (sl[i] == e) ? 1 : 0;
#pragma unroll
  for (int e = 0; e < NE; e++) hist[e * 1024 + tid] = h[e];
  __syncthreads();
  int wid = tid >> 6, lane = tid & 63;
  if (wid < NE) {
    int e = wid;
    int vals[16];
    int lsum = 0;
#pragma unroll
    for (int i = 0; i < 16; i++) {
      int v = hist[e * 1024 + lane * 16 + i];
      vals[i] = lsum;
      lsum += v;
    }
    int incl = lsum;
#pragma unroll
    for (int off = 1; off < 64; off <<= 1) {
      int v = __shfl_up(incl, off);
      if (lane >= off) incl += v;
    }
    int excl = incl - lsum;
#pragma unroll
    for (int i = 0; i < 16; i++) hist[e * 1024 + lane * 16 + i] = vals[i] + excl;
    if (lane == 63) tot[e] = incl;
  }
  __syncthreads();
  if (tid == 0) {
    int acc = 0;
    for (int e = 0; e < NE; e++) {
      offs[e] = acc;
      offsets[e] = acc;
      counts[e] = tot[e];
      acc += (tot[e] + 127) & ~127;   // 128-align every segment
    }
  }
  __syncthreads();
  int base[NE];
#pragma unroll
  for (int e = 0; e < NE; e++) base[e] = offs[e] + hist[e * 1024 + tid];
#pragma unroll
  for (int i = 0; i < 16; i++) {
    int slot = tid * 16 + i;
    int e = sl[i];
    int pos = 0;
#pragma unroll
    for (int k = 0; k < NE; k++) pos += (e == k) ? base[k] : 0;
#pragma unroll
    for (int k = 0; k < NE; k++) base[k] += (e == k) ? 1 : 0;
    slot2pos[slot] = pos;
    slot_score[pos] = selscore[slot];
  }
}

// ---------------- gather: slot -> blocked row pos of bf16(s*x) ---------------
__global__ __launch_bounds__(256) void gather_kernel(
    const u16* __restrict__ xb, const float* __restrict__ selscore,
    const int* __restrict__ slot2pos, u16* __restrict__ routed) {
  int s = blockIdx.x * 4 + (threadIdx.x >> 6);
  int lane = threadIdx.x & 63;
  int pos = slot2pos[s];
  float sc = selscore[s];
  int t = s >> 1;
#pragma unroll
  for (int j = 0; j < 4; j++) {
    int c = j * 256 + lane * 4;
    uint2 v = *(const uint2*)&xb[ablk(t, c)];
    uint2 p;
    p.x = pack2(bflo(v.x) * sc, bfhi(v.x) * sc);
    p.y = pack2(bflo(v.y) * sc, bfhi(v.y) * sc);
    *(uint2*)&routed[ablk(pos, c)] = p;
  }
}

// ============================================================================
// Pipelined GEMM core (both GEMM kernels).
// R6 POST-MORTEM: occupancy 14.4% ~= ONE 4-wave block/CU (1 wave/SIMD) ->
// every ds_read->MFMA latency and barrier wait fully exposed (MfmaUtil 18%).
// Corrected cost model: MFMA 32x32x16 is 8 cy PER CU (2495 TF / 256 CU),
// so at >=8 waves/CU the matrix pipe dominates LDS even at 1 KB/MFMA.
// => 512 threads = 8 waves/block (2 waves/SIMD guaranteed even at 1 block/CU
// -- the m201 regime) with a SMALL accumulator so nothing spills:
//  waves wy4 x wn2, wave tile 64x64 (acc 2x2 f32x16 = 64 regs; ~164 total,
//  well under the 256/wave 2-per-SIMD budget; launch_bounds(512,1)).
//  Block tile 256 rows x 128 cols, K-tile 32, LDS 3 x 24 KB = 72 KB.
//  Per CU per K-tile (8 waves): MFMA 512 cy vs LDS r+w 344 cy -> MFMA-bound.
//  Staging: 3 x gload16/thread/K-tile. Counted-vmcnt distance-2 pipeline:
//    prologue: STAGE->b0, STAGE->b1                     [6 in flight]
//    iter t:   SYNC vmcnt(3)+barrier -> tile t resident, t+1 in flight
//              STAGE -> buffer of t-1 (reads done one barrier ago)
//              setprio(1); 8 MFMA; setprio(0)
//    tail:     SYNC(3); compute; SYNC(0); compute
//  Grid + balanced XCD mapping identical to R6 (verified pass, FETCH-ideal).
// R7 was an infra failure (container acquisition), not a kernel verdict;
// kernel re-audited (barrier uniformity, vmcnt ledger, LDS map) and resubmitted.
// ============================================================================
#define BUFE 12288  // u16/buffer: A[half2][kc4][row128][8] | B[unit2][kc4][col64][8]

#define PIPE_STAGE(B)                                  \
  do {                                                 \
    u16* Lb = &lds[(B) * BUFE];                        \
    gload16(pAa, Lb + tid * 8);                        \
    gload16(pAb, Lb + 4096 + tid * 8);                 \
    gload16(pBm, Lb + 8192 + (tid >> 8) * 2048 + (tid & 255) * 8); \
    pAa += 4096; pAb += 4096; pBm += 2048;             \
  } while (0)

#define PIPE_COMPUTE(B)                                                  \
  do {                                                                   \
    _Pragma("unroll")                                                    \
    for (int c = 0; c < 2; c++) {                                        \
      int kc = 2 * c + l5;                                               \
      const u16* La = &lds[(B) * BUFE] + (wy >> 1) * 4096 + kc * 1024 +  \
                      (wy & 1) * 512;                                    \
      const u16* Lw = &lds[(B) * BUFE] + 8192 + wn * 2048 + kc * 512;    \
      bf16x8 b0 = *(const bf16x8*)&Lw[l31 * 8];                          \
      bf16x8 b1 = *(const bf16x8*)&Lw[256 + l31 * 8];                    \
      bf16x8 a0 = *(const bf16x8*)&La[l31 * 8];                          \
      acc[0][0] = MFMA32(a0, b0, acc[0][0]);                             \
      acc[0][1] = MFMA32(a0, b1, acc[0][1]);                             \
      bf16x8 a1 = *(const bf16x8*)&La[256 + l31 * 8];                    \
      acc[1][0] = MFMA32(a1, b0, acc[1][0]);                             \
      acc[1][1] = MFMA32(a1, b1, acc[1][1]);                             \
    }                                                                    \
  } while (0)

#define PIPE_PHASE(SB, CB)                  \
  PIPE_SYNC(3);                             \
  PIPE_STAGE(SB);                           \
  __builtin_amdgcn_s_setprio(1);            \
  PIPE_COMPUTE(CB);                         \
  __builtin_amdgcn_s_setprio(0);

#define PIPE_LOOP()                         \
  PIPE_STAGE(0);                            \
  PIPE_STAGE(1);                            \
  _Pragma("unroll 1")                       \
  for (int t = 0; t < 30; t += 3) {         \
    PIPE_PHASE(2, 0);                       \
    PIPE_PHASE(0, 1);                       \
    PIPE_PHASE(1, 2);                       \
  }                                         \
  PIPE_SYNC(3);                             \
  __builtin_amdgcn_s_setprio(1);            \
  PIPE_COMPUTE(0);                          \
  __builtin_amdgcn_s_setprio(0);            \
  PIPE_SYNC(0);                             \
  __builtin_amdgcn_s_setprio(1);            \
  PIPE_COMPUTE(1);                          \
  __builtin_amdgcn_s_setprio(0);

// ---------------- dual GLU GEMM ---------------------------------------------
// Block covers 64 H-cols x both matrices. B units: u0 = W1[hx*64..+64],
// u1 = W3[same]. Waves: wn=0 (4 waves, rows 0..255) compute h1; wn=1 compute
// h3. Epilogue: one f32 LDS exchange round (256x64 = 64 KB).
__global__ __launch_bounds__(512, 1) void dual_glu_gemm(
    const u16* __restrict__ A, const u16* __restrict__ W1,
    const u16* __restrict__ W3, u16* __restrict__ Hout,
    const u16* __restrict__ As, const u16* __restrict__ SW1,
    const u16* __restrict__ SW3, u16* __restrict__ Hs,
    const int* __restrict__ seg_off, const int* __restrict__ seg_cnt) {
  // balanced XCD mapping (R6-verified). GX=16, GY=32, GZ=9.
  int flat = blockIdx.x + 16 * blockIdx.y + 512 * blockIdx.z;
  int xcd = flat & 7;
  int r = flat >> 3;            // 0..575
  int bx = r & 15;
  int s = r >> 4;               // 0..35
  int z, by;
  if (s < 4) { z = NE; by = xcd * 4 + s; }       // shared-expert chunks first
  else       { z = xcd; by = s - 4; }

  const u16 *Ap, *w1p, *w3p;
  u16* Hp;
  int soff, scnt;
  if (z < NE) {
    soff = seg_off[z]; scnt = seg_cnt[z];
    Ap = A;
    w1p = W1 + (size_t)z * HIDSZ * DIMSZ;
    w3p = W3 + (size_t)z * HIDSZ * DIMSZ;
    Hp = Hout;
  } else {
    soff = 0; scnt = T_TOK;
    Ap = As; w1p = SW1; w3p = SW3;
    Hp = Hs;
  }
  int mbase = by * 256;
  if (mbase >= scnt) return;
  int hx = bx;                               // 64-H-col tile

  __shared__ u16 lds[3 * BUFE];              // 72 KB

  int tid = threadIdx.x;
  int lane = tid & 63;
  int wid = tid >> 6;
  int wy = wid >> 1, wn = wid & 1;
  int l5 = lane >> 5, l31 = lane & 31;

  const u16* pAa = Ap + (size_t)((soff + mbase) >> 7) * 32 * 4096 + tid * 8;
  const u16* pAb = pAa + 32 * 4096;
  const u16* pBm = ((tid >> 8) == 0 ? w1p : w3p) +
                   (size_t)hx * 32 * 2048 + (tid & 255) * 8;

  f32x16 acc[2][2];
  acc[0][0] = (f32x16)0.f; acc[0][1] = (f32x16)0.f;
  acc[1][0] = (f32x16)0.f; acc[1][1] = (f32x16)0.f;

  PIPE_LOOP();

  // ---- epilogue: f32 h1 exchange (wn0 -> wn1), write silu(h1)*h3 ----
  __syncthreads();
  float* ex = (float*)lds;                   // 256 rows x 64 cols f32 = 64 KB
  if (wn == 0) {
#pragma unroll
    for (int i = 0; i < 2; i++)
#pragma unroll
      for (int j = 0; j < 2; j++)
#pragma unroll
        for (int r2 = 0; r2 < 16; r2++) {
          int rowl = wy * 64 + i * 32 + (r2 & 3) + 8 * (r2 >> 2) + 4 * l5;
          ex[rowl * 64 + j * 32 + l31] = acc[i][j][r2];
        }
  }
  __syncthreads();
  if (wn == 1) {
#pragma unroll
    for (int i = 0; i < 2; i++)
#pragma unroll
      for (int j = 0; j < 2; j++)
#pragma unroll
        for (int r2 = 0; r2 < 16; r2++) {
          int rowl = wy * 64 + i * 32 + (r2 & 3) + 8 * (r2 >> 2) + 4 * l5;
          int grow = mbase + rowl;
          if (grow < scnt) {
            float h1 = ex[rowl * 64 + j * 32 + l31];
            Hp[ablk(soff + grow, hx * 64 + j * 32 + l31)] =
                f2bf(silu_f(h1) * acc[i][j][r2]);
          }
        }
  }
}

// ---------------- GEMM2: Out = (A @ W^T) * scale -----------------------------
__global__ __launch_bounds__(512, 1) void gemm2_kernel(
    const u16* __restrict__ A, const u16* __restrict__ W, u16* __restrict__ OutB,
    const u16* __restrict__ As, const u16* __restrict__ SW, float* __restrict__ OutF,
    const float* __restrict__ scale, const int* __restrict__ seg_off,
    const int* __restrict__ seg_cnt) {
  // balanced XCD mapping. GX=8, GY=32, GZ=9.
  int flat = blockIdx.x + 8 * blockIdx.y + 256 * blockIdx.z;
  int xcd = flat & 7;
  int r = flat >> 3;            // 0..287
  int bx = r & 7;
  int s = r >> 3;               // 0..35
  int z, by;
  if (s < 4) { z = NE; by = xcd * 4 + s; }
  else       { z = xcd; by = s - 4; }

  const u16 *Ap, *wp;
  int soff, scnt;
  if (z < NE) {
    soff = seg_off[z]; scnt = seg_cnt[z];
    Ap = A; wp = W + (size_t)z * DIMSZ * HIDSZ;
  } else {
    soff = 0; scnt = T_TOK;
    Ap = As; wp = SW;
  }
  int mbase = by * 256;
  if (mbase >= scnt) return;
  int nbase = bx * 128;

  __shared__ u16 lds[3 * BUFE];

  int tid = threadIdx.x;
  int lane = tid & 63;
  int wid = tid >> 6;
  int wy = wid >> 1, wn = wid & 1;
  int l5 = lane >> 5, l31 = lane & 31;

  const u16* pAa = Ap + (size_t)((soff + mbase) >> 7) * 32 * 4096 + tid * 8;
  const u16* pAb = pAa + 32 * 4096;
  const u16* pBm = wp + (size_t)((nbase >> 6) + (tid >> 8)) * 32 * 2048 +
                   (tid & 255) * 8;

  f32x16 acc[2][2];
  acc[0][0] = (f32x16)0.f; acc[0][1] = (f32x16)0.f;
  acc[1][0] = (f32x16)0.f; acc[1][1] = (f32x16)0.f;

  PIPE_LOOP();

#pragma unroll
  for (int i = 0; i < 2; i++)
#pragma unroll
    for (int j = 0; j < 2; j++) {
      int colg = nbase + wn * 64 + j * 32 + l31;
#pragma unroll
      for (int r2 = 0; r2 < 16; r2++) {
        int rowl = (r2 & 3) + 8 * (r2 >> 2) + 4 * l5;
        int grow = mbase + wy * 64 + i * 32 + rowl;
        if (grow < scnt) {
          size_t idx = (size_t)(soff + grow) * DIMSZ + colg;
          if (z < NE) {
            OutB[idx] = f2bf(acc[i][j][r2] * scale[soff + grow]);
          } else {
            OutF[idx] = acc[i][j][r2];
          }
        }
      }
    }
}

// ---------------- combine: out[t] += Or[pos(t,0)] + Or[pos(t,1)] -------------
__global__ __launch_bounds__(256) void combine_kernel(
    float* __restrict__ out, const u16* __restrict__ Orb,
    const int* __restrict__ slot2pos) {
  int t = blockIdx.x;
  int d = threadIdx.x * 4;
  int p0 = slot2pos[t * 2];
  int p1 = slot2pos[t * 2 + 1];
  float4 o = *(float4*)&out[(size_t)t * DIMSZ + d];
  uint2 a = *(const uint2*)&Orb[(size_t)p0 * DIMSZ + d];
  uint2 b = *(const uint2*)&Orb[(size_t)p1 * DIMSZ + d];
  o.x += bflo(a.x) + bflo(b.x);
  o.y += bfhi(a.x) + bfhi(b.x);
  o.z += bflo(a.y) + bflo(b.y);
  o.w += bfhi(a.y) + bfhi(b.y);
  *(float4*)&out[(size_t)t * DIMSZ + d] = o;
}

extern "C" void kernel_launch(void* const* d_in, const int* in_sizes, int n_in,
                              void* d_out, int out_size, void* d_ws, size_t ws_size,
                              hipStream_t stream) {
  const float* x = (const float*)d_in[0];
  const float* gw = (const float*)d_in[1];
  const float* w1 = (const float*)d_in[2];
  const float* w2 = (const float*)d_in[3];
  const float* w3 = (const float*)d_in[4];
  const float* sw1 = (const float*)d_in[5];
  const float* sw2 = (const float*)d_in[6];
  const float* sw3 = (const float*)d_in[7];
  const float* bias = (const float*)d_in[8];
  float* out = (float*)d_out;

  uint8_t* ws = (uint8_t*)d_ws;
  size_t off = 0;
  auto alloc = [&](size_t b) { size_t o = off; off += (b + 255) & ~(size_t)255; return o; };

  size_t ctrl = alloc(256);
  int* counts = (int*)(ws + ctrl);
  int* offsets = counts + 16;
  int* sel = (int*)(ws + alloc((size_t)NSLOT * 4));
  float* selscore = (float*)(ws + alloc((size_t)NSLOT * 4));
  float* slot_score = (float*)(ws + alloc((size_t)NPAD * 4));
  int* slot2pos = (int*)(ws + alloc((size_t)NSLOT * 4));
  u16* xb = (u16*)(ws + alloc((size_t)T_TOK * DIMSZ * 2));
  u16* routed = (u16*)(ws + alloc((size_t)NPAD * DIMSZ * 2));
  u16* Hbuf = (u16*)(ws + alloc((size_t)NPAD * HIDSZ * 2));
  u16* Orb = (u16*)(ws + alloc((size_t)NPAD * DIMSZ * 2));
  u16* Hs = (u16*)(ws + alloc((size_t)T_TOK * HIDSZ * 2));
  u16* w1b = (u16*)(ws + alloc((size_t)NE * HIDSZ * DIMSZ * 2));
  u16* w2b = (u16*)(ws + alloc((size_t)NE * DIMSZ * HIDSZ * 2));
  u16* w3b = (u16*)(ws + alloc((size_t)NE * HIDSZ * DIMSZ * 2));
  u16* sw1b = (u16*)(ws + alloc((size_t)HIDSZ * DIMSZ * 2));
  u16* sw2b = (u16*)(ws + alloc((size_t)DIMSZ * HIDSZ * 2));
  u16* sw3b = (u16*)(ws + alloc((size_t)HIDSZ * DIMSZ * 2));

  // weight conversion fp32 row-major -> bf16 blocked tiles (single launch)
  convert_blocked<<<dim3((NE + 1) * 16 * 32, 3), 256, 0, stream>>>(
      w1, w2, w3, sw1, sw2, sw3, w1b, w2b, w3b, sw1b, sw2b, sw3b);

  router_kernel<<<T_TOK / 4, 256, 0, stream>>>(x, gw, bias, sel, selscore, xb);
  rank_kernel<<<1, 1024, 0, stream>>>(sel, selscore, slot2pos, slot_score,
                                      counts, offsets);
  gather_kernel<<<NSLOT / 4, 256, 0, stream>>>(xb, selscore, slot2pos, routed);

  // unified GEMMs: z = 0..7 routed experts, z = 8 shared expert
  dual_glu_gemm<<<dim3(16, 32, NE + 1), 512, 0, stream>>>(
      routed, w1b, w3b, Hbuf, xb, sw1b, sw3b, Hs, offsets, counts);
  gemm2_kernel<<<dim3(8, 32, NE + 1), 512, 0, stream>>>(
      Hbuf, w2b, Orb, Hs, sw2b, out, slot_score, offsets, counts);

  // combine routed contributions into shared output
  combine_kernel<<<T_TOK, 256, 0, stream>>>(out, Orb, slot2pos);
}